// Round 4
// baseline (702.828 us; speedup 1.0000x reference)
//
#include <hip/hip_runtime.h>
#include <hip/hip_bf16.h>
#include <cfloat>

#define CH   1024
#define HW   4096
#define NSVD 500
#define TFR  3
#define SREF 2

typedef __attribute__((ext_vector_type(4))) float f32x4;
typedef __attribute__((ext_vector_type(4))) unsigned int u32x4;
typedef __attribute__((ext_vector_type(8))) short short8;

// ---------------------------------------------------------------------------
// ws layout (floats):
//   fnp     : 0            (3*1024*4096 packed u32; tgt frame becomes fd_t_deb)
//   invn    : 12,582,912   (3*4096)   1/||fmaps col||
//   invc    : 12,595,200   (3*4096)   refs: 1/sqrt(1-||coef||^2); tgt: 1/||Xd_t||
//   counts  : 12,607,488   (64)
//   protos  : 12,607,552   (2*1024)   masked weighted sums (pre-projection)
//   protod  : 12,609,600   (2*1024)   projected
//   proto   : 12,611,648   (1024)
//   pmax    : 12,612,672   (2*4*4096)
//   pidx    : 12,645,440   (2*4*4096 as int)
// d_out scratch (all dead before sim GEMM overwrites):
//   Pp   : out + 0          (1024*1024 packed u32)
//   bpk  : out + 1,048,576  (1024*512 packed u32, basis zero-padded to 512)
//   coef : out + 1,572,864  (2*512*4096 fp32)
//   Xd_t : out + 5,767,168  (1024*4096 fp32)
// ---------------------------------------------------------------------------

__device__ inline unsigned bfr(float x) {        // fp32 -> bf16 bits, RNE
  unsigned u = __float_as_uint(x);
  return (u + 0x7fffu + ((u >> 16) & 1u)) >> 16;
}
__device__ inline unsigned packhl(float x) {     // (bf16 hi << 16) | bf16(residual)
  unsigned h = bfr(x);
  float lo = x - __uint_as_float(h << 16);
  unsigned l = bfr(lo);
  return (h << 16) | l;
}
__device__ inline float unpackhl(unsigned p) {
  return __uint_as_float(p & 0xFFFF0000u) + __uint_as_float(p << 16);
}

// Column L2 norms over C, layout (t, c, n): invn[t*HW+n] = 1/max(||.||,1e-12)
// grid = nframes*64 blocks
__global__ __launch_bounds__(256) void colnorm_k(const float* __restrict__ src,
                                                 float* __restrict__ invn) {
  int blk = blockIdx.x;
  int t = blk >> 6;
  int n0 = (blk & 63) * 64;
  int tid = threadIdx.x;
  int nl = tid & 63, r = tid >> 6;
  const float* base = src + (size_t)t * CH * HW + n0 + nl;
  float s = 0.f;
  for (int c = r; c < CH; c += 4) {
    float v = base[(size_t)c * HW];
    s += v * v;
  }
  __shared__ float red[256];
  red[tid] = s;
  __syncthreads();
  if (r == 0) {
    float tot = red[nl] + red[nl + 64] + red[nl + 128] + red[nl + 192];
    invn[t * HW + n0 + nl] = 1.0f / fmaxf(sqrtf(tot), 1e-12f);
  }
}

// dst[t,c,n] = pack_hi_lo(src[t,c,n] * invn[t,n])
__global__ __launch_bounds__(256) void scale_pack_k(const float* __restrict__ src,
                                                    const float* __restrict__ invn,
                                                    unsigned* __restrict__ dst) {
  size_t i = ((size_t)blockIdx.x * 256 + threadIdx.x) * 4;
  int t = (int)(i / ((size_t)CH * HW));
  int n = (int)(i & (HW - 1));
  float4 v = *reinterpret_cast<const float4*>(src + i);
  float4 w = *reinterpret_cast<const float4*>(invn + t * HW + n);
  u32x4 o;
  o.x = packhl(v.x * w.x);
  o.y = packhl(v.y * w.y);
  o.z = packhl(v.z * w.z);
  o.w = packhl(v.w * w.w);
  *reinterpret_cast<u32x4*>(dst + i) = o;
}

// bpk[c*512+m] = packhl(m<500 ? basis[c*500+m] : 0)
__global__ __launch_bounds__(256) void pack_basis_k(const float* __restrict__ bas,
                                                    unsigned* __restrict__ bpk) {
  int g = blockIdx.x * 256 + threadIdx.x;      // 0 .. 524287
  int c = g >> 9, m = g & 511;
  float v = (m < NSVD) ? bas[c * NSVD + m] : 0.f;
  bpk[g] = packhl(v);
}

// Pp = pack(I - basis @ basis^T)   — 1024x1024, symmetric.
__global__ __launch_bounds__(256) void proj_pack_k(const float* __restrict__ bas,
                                                   unsigned* __restrict__ Pp) {
  int m0 = blockIdx.x * 64, n0 = blockIdx.y * 64;
  int tid = threadIdx.x;
  int tx = tid & 15, ty = tid >> 4;
  int lm = tid & 63, lk = tid >> 6;
  __shared__ float As[16][64];
  __shared__ float Bs[16][64];
  float acc[4][4] = {};
  for (int k0 = 0; k0 < 512; k0 += 16) {
#pragma unroll
    for (int i = 0; i < 4; i++) {
      int k = k0 + lk * 4 + i;
      As[lk * 4 + i][lm] = (k < NSVD) ? bas[(size_t)(m0 + lm) * NSVD + k] : 0.f;
      Bs[lk * 4 + i][lm] = (k < NSVD) ? bas[(size_t)(n0 + lm) * NSVD + k] : 0.f;
    }
    __syncthreads();
#pragma unroll
    for (int kk = 0; kk < 16; kk++) {
      float a[4], b[4];
#pragma unroll
      for (int i = 0; i < 4; i++) a[i] = As[kk][ty * 4 + i];
#pragma unroll
      for (int j = 0; j < 4; j++) b[j] = Bs[kk][tx * 4 + j];
#pragma unroll
      for (int i = 0; i < 4; i++)
#pragma unroll
        for (int j = 0; j < 4; j++) acc[i][j] += a[i] * b[j];
    }
    __syncthreads();
  }
#pragma unroll
  for (int i = 0; i < 4; i++) {
    int m = m0 + ty * 4 + i;
#pragma unroll
    for (int j = 0; j < 4; j++) {
      int n = n0 + tx * 4 + j;
      float v = ((m == n) ? 1.0f : 0.0f) - acc[i][j];
      Pp[(size_t)m * CH + n] = packhl(v);
    }
  }
}

// invc[s*HW+n] = 1/max(sqrt(max(1 - sum_m coef^2, 0)), 1e-12)   (refs)
__global__ __launch_bounds__(256) void normref_k(const float* __restrict__ coef,
                                                 float* __restrict__ invc) {
  int n = blockIdx.x * 256 + threadIdx.x;
  int s = blockIdx.y;
  const float* col = coef + (size_t)s * 512 * HW + n;
  float s2 = 0.f;
  for (int m = 0; m < 512; m++) {
    float v = col[(size_t)m * HW];
    s2 += v * v;
  }
  invc[s * HW + n] = 1.0f / fmaxf(sqrtf(fmaxf(1.0f - s2, 0.0f)), 1e-12f);
}

__global__ __launch_bounds__(256) void count_k(const int* __restrict__ mask,
                                               float* __restrict__ counts) {
  int s = blockIdx.x;
  int tid = threadIdx.x;
  int c = 0;
  for (int i = tid; i < HW; i += 256) c += (mask[s * HW + i] != 0);
  __shared__ int red[256];
  red[tid] = c;
  __syncthreads();
  for (int o = 128; o > 0; o >>= 1) {
    if (tid < o) red[tid] += red[tid + o];
    __syncthreads();
  }
  if (tid == 0) counts[s] = fmaxf((float)red[0], 1.0f);
}

// protos[s*CH+c] = sum_n mask[s,n] * fn_r[c,n] * invc[s,n]   (pre-projection)
__global__ __launch_bounds__(256) void proto_k(const unsigned* __restrict__ fnp,
                                               const int* __restrict__ mask,
                                               const float* __restrict__ invc,
                                               float* __restrict__ protos) {
  int s = blockIdx.x >> 10, c = blockIdx.x & 1023;
  int tid = threadIdx.x;
  const unsigned* row = fnp + ((size_t)s * CH + c) * HW;
  const int* mrow = mask + s * HW;
  const float* wrow = invc + s * HW;
  float acc = 0.f;
  for (int i = tid; i < HW; i += 256)
    acc += mrow[i] ? unpackhl(row[i]) * wrow[i] : 0.f;
  __shared__ float red[256];
  red[tid] = acc;
  __syncthreads();
  for (int o = 128; o > 0; o >>= 1) {
    if (tid < o) red[tid] += red[tid + o];
    __syncthreads();
  }
  if (tid == 0) protos[blockIdx.x] = red[0];
}

// protod[s*CH+c] = sum_k P[c,k] * protos[s*CH+k]   (P symmetric: read Pp[k*CH+c])
__global__ __launch_bounds__(256) void protomv_k(const unsigned* __restrict__ Pp,
                                                 const float* __restrict__ protos,
                                                 float* __restrict__ protod) {
  int s = blockIdx.x >> 2;
  int c = (blockIdx.x & 3) * 256 + threadIdx.x;
  __shared__ float w[CH];
  for (int k = threadIdx.x; k < CH; k += 256) w[k] = protos[s * CH + k];
  __syncthreads();
  float acc = 0.f;
  for (int k = 0; k < CH; k++) acc += unpackhl(Pp[(size_t)k * CH + c]) * w[k];
  protod[s * CH + c] = acc;
}

__global__ __launch_bounds__(256) void protonorm_k(const float* __restrict__ protod,
                                                   const float* __restrict__ counts,
                                                   float* __restrict__ proto) {
  int tid = threadIdx.x;
  __shared__ float sm[CH];
  __shared__ float red[256];
  float c0 = counts[0], c1 = counts[1];
  float ss = 0.f;
  for (int c = tid; c < CH; c += 256) {
    float m = 0.5f * (protod[c] / c0 + protod[CH + c] / c1);
    sm[c] = m;
    ss += m * m;
  }
  red[tid] = ss;
  __syncthreads();
  for (int o = 128; o > 0; o >>= 1) {
    if (tid < o) red[tid] += red[tid + o];
    __syncthreads();
  }
  __syncthreads();
  float inv = 1.0f / fmaxf(sqrtf(red[0]), 1e-12f);
  for (int c = tid; c < CH; c += 256) proto[c] = sm[c] * inv;
}

__global__ __launch_bounds__(256) void simfwd_k(const unsigned* __restrict__ fd,
                                                const float* __restrict__ proto,
                                                float* __restrict__ out) {
  __shared__ float p[CH];
  for (int c = threadIdx.x; c < CH; c += 256) p[c] = proto[c];
  __syncthreads();
  int n = blockIdx.x * 256 + threadIdx.x;
  const unsigned* tgt = fd + (size_t)2 * CH * HW + n;
  float s = 0.f;
  for (int c = 0; c < CH; c++) s += unpackhl(tgt[(size_t)c * HW]) * p[c];
  out[n] = s;
}

// ---------------------------------------------------------------------------
// Generic split-bf16 TN GEMM: C[m,n] = rs[m] * sum_k A[k*lda+m]*B[k*ldb+n],
// K=1024 fixed. A,B packed u32 = (bf16hi<<16)|bf16lo; 3 MFMA passes.
// 128x128 tile, BK=32, 4 waves each 64x64 quadrant of 4x4 16x16x32 frags.
// ---------------------------------------------------------------------------
#define BM 128
#define BK 32

__global__ __launch_bounds__(256) void gemm3_tn_k(
    const unsigned* __restrict__ Ag0, int lda, size_t sA,
    const unsigned* __restrict__ Bg0, int ldb, size_t sB,
    float* __restrict__ Cg0, int ldc, size_t sC,
    const float* __restrict__ rs0, size_t sRS) {
  const unsigned* Ag = Ag0 + (size_t)blockIdx.z * sA;
  const unsigned* Bg = Bg0 + (size_t)blockIdx.z * sB;
  float* Cout = Cg0 + (size_t)blockIdx.z * sC;
  const float* rs = rs0 ? rs0 + (size_t)blockIdx.z * sRS : (const float*)0;
  int m0 = blockIdx.x * BM, n0 = blockIdx.y * BM;

  __shared__ unsigned As[BM * BK];   // 16 KB
  __shared__ unsigned Bs[BM * BK];   // 16 KB

  int tid = threadIdx.x;
  int lane = tid & 63, wave = tid >> 6;
  int wr = wave >> 1, wc = wave & 1;

  int sm = tid & 127;          // staged row (m or n)
  int skh = tid >> 7;          // k-half 0/1

  int fcol = lane & 15;        // fragment m/n index
  int fkb = (lane >> 4) * 2;   // fragment kb base (16B blocks of 4 u32)

  f32x4 acc[4][4] = {};
  unsigned ra[16], rb[16];

#define LOADT(KT)                                                            \
  {                                                                          \
    const unsigned* pa = Ag + (size_t)((KT) * BK + skh * 16) * lda + m0 + sm; \
    const unsigned* pb = Bg + (size_t)((KT) * BK + skh * 16) * ldb + n0 + sm; \
    _Pragma("unroll")                                                        \
    for (int i = 0; i < 16; i++) {                                           \
      ra[i] = pa[(size_t)i * lda];                                           \
      rb[i] = pb[(size_t)i * ldb];                                           \
    }                                                                        \
  }

  LOADT(0);

  for (int kt = 0; kt < CH / BK; ++kt) {
    __syncthreads();
#pragma unroll
    for (int b = 0; b < 4; b++) {
      int kbs = ((skh * 4 + b) ^ (sm & 7)) * 4;
      u32x4 wa = {ra[b * 4 + 0], ra[b * 4 + 1], ra[b * 4 + 2], ra[b * 4 + 3]};
      u32x4 wb = {rb[b * 4 + 0], rb[b * 4 + 1], rb[b * 4 + 2], rb[b * 4 + 3]};
      *reinterpret_cast<u32x4*>(&As[sm * BK + kbs]) = wa;
      *reinterpret_cast<u32x4*>(&Bs[sm * BK + kbs]) = wb;
    }
    __syncthreads();

    if (kt + 1 < CH / BK) LOADT(kt + 1);   // prefetch hides under MFMA

    short8 bh[4], bl[4];
#pragma unroll
    for (int nf = 0; nf < 4; nf++) {
      int nloc = wc * 64 + nf * 16 + fcol;
      const unsigned* rowp = &Bs[nloc * BK];
      u32x4 p0 = *reinterpret_cast<const u32x4*>(&rowp[((fkb) ^ (nloc & 7)) * 4]);
      u32x4 p1 = *reinterpret_cast<const u32x4*>(&rowp[((fkb + 1) ^ (nloc & 7)) * 4]);
      u32x4 h, l;
      h.x = __builtin_amdgcn_perm(p0.y, p0.x, 0x07060302u);
      h.y = __builtin_amdgcn_perm(p0.w, p0.z, 0x07060302u);
      h.z = __builtin_amdgcn_perm(p1.y, p1.x, 0x07060302u);
      h.w = __builtin_amdgcn_perm(p1.w, p1.z, 0x07060302u);
      l.x = __builtin_amdgcn_perm(p0.y, p0.x, 0x05040100u);
      l.y = __builtin_amdgcn_perm(p0.w, p0.z, 0x05040100u);
      l.z = __builtin_amdgcn_perm(p1.y, p1.x, 0x05040100u);
      l.w = __builtin_amdgcn_perm(p1.w, p1.z, 0x05040100u);
      bh[nf] = __builtin_bit_cast(short8, h);
      bl[nf] = __builtin_bit_cast(short8, l);
    }
#pragma unroll
    for (int mf = 0; mf < 4; mf++) {
      int mloc = wr * 64 + mf * 16 + fcol;
      const unsigned* rowp = &As[mloc * BK];
      u32x4 p0 = *reinterpret_cast<const u32x4*>(&rowp[((fkb) ^ (mloc & 7)) * 4]);
      u32x4 p1 = *reinterpret_cast<const u32x4*>(&rowp[((fkb + 1) ^ (mloc & 7)) * 4]);
      u32x4 h, l;
      h.x = __builtin_amdgcn_perm(p0.y, p0.x, 0x07060302u);
      h.y = __builtin_amdgcn_perm(p0.w, p0.z, 0x07060302u);
      h.z = __builtin_amdgcn_perm(p1.y, p1.x, 0x07060302u);
      h.w = __builtin_amdgcn_perm(p1.w, p1.z, 0x07060302u);
      l.x = __builtin_amdgcn_perm(p0.y, p0.x, 0x05040100u);
      l.y = __builtin_amdgcn_perm(p0.w, p0.z, 0x05040100u);
      l.z = __builtin_amdgcn_perm(p1.y, p1.x, 0x05040100u);
      l.w = __builtin_amdgcn_perm(p1.w, p1.z, 0x05040100u);
      short8 ah = __builtin_bit_cast(short8, h);
      short8 al = __builtin_bit_cast(short8, l);
#pragma unroll
      for (int nf = 0; nf < 4; nf++) {
        acc[mf][nf] = __builtin_amdgcn_mfma_f32_16x16x32_bf16(ah, bh[nf], acc[mf][nf], 0, 0, 0);
        acc[mf][nf] = __builtin_amdgcn_mfma_f32_16x16x32_bf16(ah, bl[nf], acc[mf][nf], 0, 0, 0);
        acc[mf][nf] = __builtin_amdgcn_mfma_f32_16x16x32_bf16(al, bh[nf], acc[mf][nf], 0, 0, 0);
      }
    }
  }
#undef LOADT

  int rbase = (lane >> 4) * 4;
#pragma unroll
  for (int mf = 0; mf < 4; mf++) {
    int mbase = m0 + wr * 64 + mf * 16 + rbase;
#pragma unroll
    for (int r = 0; r < 4; r++) {
      float sc = rs0 ? rs[mbase + r] : 1.0f;
#pragma unroll
      for (int nf = 0; nf < 4; nf++) {
        int n = n0 + wc * 64 + nf * 16 + fcol;
        Cout[(size_t)(mbase + r) * ldc + n] = acc[mf][nf][r] * sc;
      }
    }
  }
}

// Partial argmax over hw chunks of 1024; first-occurrence tie-break.
__global__ __launch_bounds__(256) void argmax_part_k(const float* __restrict__ sim,
                                                     float* __restrict__ pmax,
                                                     int* __restrict__ pidx) {
  int s = blockIdx.z, hwc = blockIdx.y, xy0 = blockIdx.x * 64;
  int tid = threadIdx.x, xl = tid & 63, r = tid >> 6;
  const float* base = sim + ((size_t)s * HW + hwc * 1024) * HW + xy0 + xl;
  float bv = -FLT_MAX;
  int bi = 0x7fffffff;
  for (int t = 0; t < 256; t++) {
    int hw = r + 4 * t;
    float v = base[(size_t)hw * HW];
    if (v > bv) { bv = v; bi = hwc * 1024 + hw; }
  }
  __shared__ float sv[256];
  __shared__ int si[256];
  sv[tid] = bv;
  si[tid] = bi;
  __syncthreads();
  if (r == 0) {
    for (int rr = 1; rr < 4; rr++) {
      float v = sv[tid + 64 * rr];
      int i = si[tid + 64 * rr];
      if (v > bv || (v == bv && i < bi)) { bv = v; bi = i; }
    }
    int o = (s * 4 + hwc) * HW + xy0 + xl;
    pmax[o] = bv;
    pidx[o] = bi;
  }
}

__global__ __launch_bounds__(256) void votes_k(const float* __restrict__ pmax,
                                               const int* __restrict__ pidx,
                                               const int* __restrict__ mask,
                                               float* __restrict__ out) {
  int xy = blockIdx.x * 256 + threadIdx.x;
  int vote = 0;
  for (int s = 0; s < SREF; s++) {
    float bv = -FLT_MAX;
    int bi = 0x7fffffff;
    for (int hwc = 0; hwc < 4; hwc++) {
      int o = (s * 4 + hwc) * HW + xy;
      float v = pmax[o];
      int i = pidx[o];
      if (v > bv || (v == bv && i < bi)) { bv = v; bi = i; }
    }
    vote += (mask[s * HW + bi] != 0);
  }
  out[xy] = (float)vote;
}

extern "C" void kernel_launch(void* const* d_in, const int* in_sizes, int n_in,
                              void* d_out, int out_size, void* d_ws, size_t ws_size,
                              hipStream_t stream) {
  const float* fmaps = (const float*)d_in[0];
  const int* mask = (const int*)d_in[1];
  const float* basis = (const float*)d_in[2];
  float* out = (float*)d_out;
  float* ws = (float*)d_ws;

  unsigned* fnp = (unsigned*)ws;          // packed hi/lo, 3 frames
  float* invn = ws + 12582912;
  float* invc = ws + 12595200;
  float* counts = ws + 12607488;
  float* protos = ws + 12607552;
  float* protod = ws + 12609600;
  float* proto = ws + 12611648;
  float* pmax = ws + 12612672;
  int* pidx = (int*)(ws + 12645440);

  float* sim = out;
  float* simfwd = out + 33554432;
  float* votes = out + 33558528;
  // out-region scratch (dead before sim GEMM writes):
  unsigned* Pp = (unsigned*)out;                    // 1M u32
  unsigned* bpk = (unsigned*)(out + 1048576);       // 512K u32
  float* coef = out + 1572864;                      // 2*512*4096 fp32
  float* Xd = out + 5767168;                        // 1024*4096 fp32

  // 1) fn = l2norm(fmaps, axis=C), packed hi/lo (3 frames)
  colnorm_k<<<dim3(TFR * 64), 256, 0, stream>>>(fmaps, invn);
  scale_pack_k<<<dim3(TFR * CH * HW / 1024), 256, 0, stream>>>(fmaps, invn, fnp);

  // 2) packed projector & padded basis
  proj_pack_k<<<dim3(16, 16), 256, 0, stream>>>(basis, Pp);
  pack_basis_k<<<dim3(2048), 256, 0, stream>>>(basis, bpk);

  // 3) coef = basis^T @ fn_refs (M=512 padded) -> ref debiased norms via 1-||coef||^2
  gemm3_tn_k<<<dim3(4, 32, 2), 256, 0, stream>>>(
      bpk, 512, 0, fnp, HW, (size_t)CH * HW, coef, HW, (size_t)512 * HW,
      (const float*)0, 0);
  normref_k<<<dim3(16, 2), 256, 0, stream>>>(coef, invc);

  // 4) Xd_t = P @ fn_tgt, its colnorm, renormalize+repack into fnp tgt frame
  gemm3_tn_k<<<dim3(8, 32, 1), 256, 0, stream>>>(
      Pp, CH, 0, fnp + (size_t)2 * CH * HW, HW, 0, Xd, HW, 0,
      (const float*)0, 0);
  colnorm_k<<<dim3(64), 256, 0, stream>>>(Xd, invc + 2 * HW);
  scale_pack_k<<<dim3(CH * HW / 1024), 256, 0, stream>>>(
      Xd, invc + 2 * HW, fnp + (size_t)2 * CH * HW);

  // 5) prototype: masked weighted sum -> project -> mean -> normalize
  count_k<<<2, 256, 0, stream>>>(mask, counts);
  proto_k<<<2048, 256, 0, stream>>>(fnp, mask, invc, protos);
  protomv_k<<<8, 256, 0, stream>>>(Pp, protos, protod);
  protonorm_k<<<1, 256, 0, stream>>>(protod, counts, proto);

  // 6) sim_fwd (tgt frame already debiased+normalized)
  simfwd_k<<<16, 256, 0, stream>>>(fnp, proto, simfwd);

  // 7) sim = diag(invnr) . fn_refs^T @ fd_tgt_deb   (projector idempotency)
  gemm3_tn_k<<<dim3(32, 32, 2), 256, 0, stream>>>(
      fnp, HW, (size_t)CH * HW, fnp + (size_t)2 * CH * HW, HW, 0, sim, HW,
      (size_t)HW * HW, invc, HW);

  // 8) votes
  argmax_part_k<<<dim3(64, 4, 2), 256, 0, stream>>>(sim, pmax, pidx);
  votes_k<<<16, 256, 0, stream>>>(pmax, pidx, mask, votes);
}

// Round 5
// 667.613 us; speedup vs baseline: 1.0527x; 1.0527x over previous
//
#include <hip/hip_runtime.h>
#include <hip/hip_bf16.h>
#include <cfloat>

#define CH   1024
#define HW   4096
#define NSVD 500
#define TFR  3
#define SREF 2

typedef __attribute__((ext_vector_type(4))) float f32x4;
typedef __attribute__((ext_vector_type(4))) unsigned int u32x4;
typedef __attribute__((ext_vector_type(8))) short short8;

// ---------------------------------------------------------------------------
// Split-bf16 plane format: value x = hi + lo (both bf16). Global planes hold
// channel-PAIRS per u32: H[t][c/2][n] = bf16hi(x[c,n]) | bf16hi(x[c+1,n])<<16.
// ws layout (float units):
//   fh   : 0          (3*512*4096 u32)  hi plane
//   fl   : 6,291,456  (3*512*4096 u32)  lo plane
//   invn : 12,582,912 (3*4096)
//   invc : 12,595,200 (3*4096)  refs: 1/sqrt(1-||coef||^2); tgt: 1/||Xd_t||
//   counts/protos/protod/proto/pmax/pidx follow
// d_out scratch (dead before sim GEMM writes):
//   Acomb_h: 0          (512*1536 u32)  [k-pair][m]: cols 0..1023 = P, 1024.. = basis
//   Acomb_l: 786,432
//   coef   : 1,572,864  (2*512*4096 f32)
//   Xd     : 5,767,168  (1024*4096 f32)
// ---------------------------------------------------------------------------

__device__ inline unsigned bfr(float x) {        // fp32 -> bf16 bits, RNE
  unsigned u = __float_as_uint(x);
  return (u + 0x7fffu + ((u >> 16) & 1u)) >> 16;
}
__device__ inline float lores(float x, unsigned h) {   // residual after hi
  return x - __uint_as_float(h << 16);
}
__device__ inline float vlo(unsigned ph, unsigned pl) {   // value of LOW half-pair
  return __uint_as_float(ph << 16) + __uint_as_float(pl << 16);
}
__device__ inline float vhi(unsigned ph, unsigned pl) {   // value of HIGH half-pair
  return __uint_as_float(ph & 0xFFFF0000u) + __uint_as_float(pl & 0xFFFF0000u);
}

// Column L2 norms over C, layout (t, c, n): inv[t*HW+n] = 1/max(||.||,1e-12)
__global__ __launch_bounds__(256) void colnorm_k(const float* __restrict__ src,
                                                 float* __restrict__ inv) {
  int blk = blockIdx.x;
  int t = blk >> 6;
  int n0 = (blk & 63) * 64;
  int tid = threadIdx.x;
  int nl = tid & 63, r = tid >> 6;
  const float* base = src + (size_t)t * CH * HW + n0 + nl;
  float s = 0.f;
  for (int c = r; c < CH; c += 4) {
    float v = base[(size_t)c * HW];
    s += v * v;
  }
  __shared__ float red[256];
  red[tid] = s;
  __syncthreads();
  if (r == 0) {
    float tot = red[nl] + red[nl + 64] + red[nl + 128] + red[nl + 192];
    inv[t * HW + n0 + nl] = 1.0f / fmaxf(sqrtf(tot), 1e-12f);
  }
}

// planes <- pack(src[t,c,n] * inv[t,n]); thread: one (t, c-pair), 4 n's
__global__ __launch_bounds__(256) void scale_pack_k(const float* __restrict__ src,
                                                    const float* __restrict__ inv,
                                                    unsigned* __restrict__ Hh,
                                                    unsigned* __restrict__ Hl) {
  int gid = blockIdx.x * 256 + threadIdx.x;
  int t = gid >> 19;
  int c2 = (gid >> 10) & 511;
  int n4 = (gid & 1023) << 2;
  const float* r0 = src + ((size_t)t * CH + 2 * c2) * HW + n4;
  float4 v0 = *reinterpret_cast<const float4*>(r0);
  float4 v1 = *reinterpret_cast<const float4*>(r0 + HW);
  float4 w = *reinterpret_cast<const float4*>(inv + t * HW + n4);
  float a0[4] = {v0.x * w.x, v0.y * w.y, v0.z * w.z, v0.w * w.w};
  float a1[4] = {v1.x * w.x, v1.y * w.y, v1.z * w.z, v1.w * w.w};
  u32x4 oh, ol;
#pragma unroll
  for (int i = 0; i < 4; i++) {
    unsigned h0 = bfr(a0[i]), h1 = bfr(a1[i]);
    unsigned l0 = bfr(lores(a0[i], h0)), l1 = bfr(lores(a1[i], h1));
    oh[i] = h0 | (h1 << 16);
    ol[i] = l0 | (l1 << 16);
  }
  size_t o = ((size_t)t * 512 + c2) * HW + n4;
  *reinterpret_cast<u32x4*>(Hh + o) = oh;
  *reinterpret_cast<u32x4*>(Hl + o) = ol;
}

// Acomb cols 0..1023: P = I - basis@basis^T, stored [k/2][m] (uses symmetry)
__global__ __launch_bounds__(256) void proj_pack_k(const float* __restrict__ bas,
                                                   unsigned* __restrict__ Ah,
                                                   unsigned* __restrict__ Al) {
  int m0 = blockIdx.x * 64, n0 = blockIdx.y * 64;
  int tid = threadIdx.x;
  int tx = tid & 15, ty = tid >> 4;
  int lm = tid & 63, lk = tid >> 6;
  __shared__ float As[16][64];
  __shared__ float Bs[16][64];
  float acc[4][4] = {};
  for (int k0 = 0; k0 < 512; k0 += 16) {
#pragma unroll
    for (int i = 0; i < 4; i++) {
      int k = k0 + lk * 4 + i;
      As[lk * 4 + i][lm] = (k < NSVD) ? bas[(size_t)(m0 + lm) * NSVD + k] : 0.f;
      Bs[lk * 4 + i][lm] = (k < NSVD) ? bas[(size_t)(n0 + lm) * NSVD + k] : 0.f;
    }
    __syncthreads();
#pragma unroll
    for (int kk = 0; kk < 16; kk++) {
      float a[4], b[4];
#pragma unroll
      for (int i = 0; i < 4; i++) a[i] = As[kk][ty * 4 + i];
#pragma unroll
      for (int j = 0; j < 4; j++) b[j] = Bs[kk][tx * 4 + j];
#pragma unroll
      for (int i = 0; i < 4; i++)
#pragma unroll
        for (int j = 0; j < 4; j++) acc[i][j] += a[i] * b[j];
    }
    __syncthreads();
  }
  // P[m][n] pairs along n -> Acomb[(n/2)][m]
#pragma unroll
  for (int jp = 0; jp < 2; jp++) {
    u32x4 oh, ol;
#pragma unroll
    for (int i = 0; i < 4; i++) {
      int m = m0 + ty * 4 + i;
      int na = n0 + tx * 4 + 2 * jp, nb = na + 1;
      float va = ((m == na) ? 1.0f : 0.0f) - acc[i][2 * jp];
      float vb = ((m == nb) ? 1.0f : 0.0f) - acc[i][2 * jp + 1];
      unsigned ha = bfr(va), hb = bfr(vb);
      oh[i] = ha | (hb << 16);
      ol[i] = bfr(lores(va, ha)) | (bfr(lores(vb, hb)) << 16);
    }
    size_t r = (size_t)((n0 + tx * 4) / 2 + jp) * 1536 + m0 + ty * 4;
    *reinterpret_cast<u32x4*>(Ah + r) = oh;
    *reinterpret_cast<u32x4*>(Al + r) = ol;
  }
}

// Acomb cols 1024..1535: basis [c][svd] zero-padded to 512, pairs along c
__global__ __launch_bounds__(256) void pack_basis_k(const float* __restrict__ bas,
                                                    unsigned* __restrict__ Ah,
                                                    unsigned* __restrict__ Al) {
  int r = blockIdx.x;            // c-pair
  for (int m = threadIdx.x; m < 512; m += 256) {
    float b0 = (m < NSVD) ? bas[(size_t)(2 * r) * NSVD + m] : 0.f;
    float b1 = (m < NSVD) ? bas[(size_t)(2 * r + 1) * NSVD + m] : 0.f;
    unsigned h0 = bfr(b0), h1 = bfr(b1);
    size_t o = (size_t)r * 1536 + 1024 + m;
    Ah[o] = h0 | (h1 << 16);
    Al[o] = bfr(lores(b0, h0)) | (bfr(lores(b1, h1)) << 16);
  }
}

// invc[s*HW+n] = 1/max(sqrt(max(1 - sum_m coef^2, 0)), 1e-12)
__global__ __launch_bounds__(256) void normref_k(const float* __restrict__ coef,
                                                 float* __restrict__ invc) {
  int s = blockIdx.y;
  int n0 = blockIdx.x * 64;
  int tid = threadIdx.x, nl = tid & 63, r = tid >> 6;
  const float* base = coef + (size_t)s * 512 * HW + n0 + nl;
  float s2 = 0.f;
  for (int m = r; m < 512; m += 4) {
    float v = base[(size_t)m * HW];
    s2 += v * v;
  }
  __shared__ float red[256];
  red[tid] = s2;
  __syncthreads();
  if (r == 0) {
    float tot = red[nl] + red[nl + 64] + red[nl + 128] + red[nl + 192];
    invc[s * HW + n0 + nl] = 1.0f / fmaxf(sqrtf(fmaxf(1.0f - tot, 0.0f)), 1e-12f);
  }
}

__global__ __launch_bounds__(256) void count_k(const int* __restrict__ mask,
                                               float* __restrict__ counts) {
  int s = blockIdx.x;
  int tid = threadIdx.x;
  int c = 0;
  for (int i = tid; i < HW; i += 256) c += (mask[s * HW + i] != 0);
  __shared__ int red[256];
  red[tid] = c;
  __syncthreads();
  for (int o = 128; o > 0; o >>= 1) {
    if (tid < o) red[tid] += red[tid + o];
    __syncthreads();
  }
  if (tid == 0) counts[s] = fmaxf((float)red[0], 1.0f);
}

// protos[s*CH + c] = sum_n mask[s,n] * fn[c,n] * invc[s,n]; block = (s, c-pair)
__global__ __launch_bounds__(256) void proto_k(const unsigned* __restrict__ Hh,
                                               const unsigned* __restrict__ Hl,
                                               const int* __restrict__ mask,
                                               const float* __restrict__ invc,
                                               float* __restrict__ protos) {
  int s = blockIdx.x >> 9, c2 = blockIdx.x & 511;
  int tid = threadIdx.x;
  size_t o = ((size_t)s * 512 + c2) * HW;
  const int* mrow = mask + s * HW;
  const float* wrow = invc + s * HW;
  float a0 = 0.f, a1 = 0.f;
  for (int i = tid; i < HW; i += 256) {
    if (mrow[i]) {
      unsigned h = Hh[o + i], l = Hl[o + i];
      float w = wrow[i];
      a0 += vlo(h, l) * w;
      a1 += vhi(h, l) * w;
    }
  }
  __shared__ float r0[256], r1[256];
  r0[tid] = a0; r1[tid] = a1;
  __syncthreads();
  for (int o2 = 128; o2 > 0; o2 >>= 1) {
    if (tid < o2) { r0[tid] += r0[tid + o2]; r1[tid] += r1[tid + o2]; }
    __syncthreads();
  }
  if (tid == 0) {
    protos[s * CH + 2 * c2] = r0[0];
    protos[s * CH + 2 * c2 + 1] = r1[0];
  }
}

// protod[s*CH+c] = sum_k P[c][k]*protos[s*CH+k]  (P sym; Acomb[k/2][c], lda 1536)
__global__ __launch_bounds__(256) void protomv_k(const unsigned* __restrict__ Ah,
                                                 const unsigned* __restrict__ Al,
                                                 const float* __restrict__ protos,
                                                 float* __restrict__ protod) {
  int s = blockIdx.x >> 2;
  int c = (blockIdx.x & 3) * 256 + threadIdx.x;
  __shared__ float w[CH];
  for (int k = threadIdx.x; k < CH; k += 256) w[k] = protos[s * CH + k];
  __syncthreads();
  float acc = 0.f;
  for (int r = 0; r < 512; r++) {
    unsigned h = Ah[(size_t)r * 1536 + c], l = Al[(size_t)r * 1536 + c];
    acc += vlo(h, l) * w[2 * r] + vhi(h, l) * w[2 * r + 1];
  }
  protod[s * CH + c] = acc;
}

__global__ __launch_bounds__(256) void protonorm_k(const float* __restrict__ protod,
                                                   const float* __restrict__ counts,
                                                   float* __restrict__ proto) {
  int tid = threadIdx.x;
  __shared__ float sm[CH];
  __shared__ float red[256];
  float c0 = counts[0], c1 = counts[1];
  float ss = 0.f;
  for (int c = tid; c < CH; c += 256) {
    float m = 0.5f * (protod[c] / c0 + protod[CH + c] / c1);
    sm[c] = m;
    ss += m * m;
  }
  red[tid] = ss;
  __syncthreads();
  for (int o = 128; o > 0; o >>= 1) {
    if (tid < o) red[tid] += red[tid + o];
    __syncthreads();
  }
  __syncthreads();
  float inv = 1.0f / fmaxf(sqrtf(red[0]), 1e-12f);
  for (int c = tid; c < CH; c += 256) proto[c] = sm[c] * inv;
}

// sim_fwd[n] = sum_c tgt[c][n]*proto[c]; 64 blocks, 4-way c-split
__global__ __launch_bounds__(256) void simfwd_k(const unsigned* __restrict__ Hh,
                                                const unsigned* __restrict__ Hl,
                                                const float* __restrict__ proto,
                                                float* __restrict__ out) {
  __shared__ float p[CH];
  __shared__ float red[256];
  int tid = threadIdx.x;
  for (int c = tid; c < CH; c += 256) p[c] = proto[c];
  __syncthreads();
  int nl = tid & 63, r = tid >> 6;
  int n = blockIdx.x * 64 + nl;
  size_t base = (size_t)(2 * 512) * HW + n;
  float acc = 0.f;
  for (int c2 = r; c2 < 512; c2 += 4) {
    unsigned h = Hh[base + (size_t)c2 * HW], l = Hl[base + (size_t)c2 * HW];
    acc += vlo(h, l) * p[2 * c2] + vhi(h, l) * p[2 * c2 + 1];
  }
  red[tid] = acc;
  __syncthreads();
  if (r == 0) out[n] = red[nl] + red[nl + 64] + red[nl + 128] + red[nl + 192];
}

// ---------------------------------------------------------------------------
// Split-bf16 plane TN GEMM, K=1024: C[m,n] = rs[m]*sum_k A[k][m]*B[k][n].
// LDS row = 128B {hi(32 bf16) | lo(32 bf16)}, 16B quads XOR-swizzled q^(row&7).
// Fragment = one ds_read_b128 (direct short8 MFMA operand). No perms.
// mode 0: batched debias (A=Acomb lda 1536; z<2 & bx>=8 -> coef; z==2 & bx<8 -> Xd)
// mode 1: sim (A=fn frame z, rs=invc row-scale, XCD-swizzled grid)
// ---------------------------------------------------------------------------
#define BM 128
#define BK 32

__device__ __forceinline__ short8 ldfrag(const unsigned* S, int loc, int q) {
  return *reinterpret_cast<const short8*>(&S[loc * 32 + ((q ^ (loc & 7)) << 2)]);
}

__global__ __launch_bounds__(256) void gemm3p_k(
    const unsigned* __restrict__ Ah0, const unsigned* __restrict__ Al0,
    int lda, size_t sA,
    const unsigned* __restrict__ Bh0, const unsigned* __restrict__ Bl0,
    size_t sB,
    float* __restrict__ C0, size_t sC, float* __restrict__ C1,
    const float* __restrict__ rs0, int mode, int swz) {
  int bx = blockIdx.x, by = blockIdx.y, bz = blockIdx.z;
  if (swz) {
    int lin = (bz * 32 + by) * 32 + bx;
    int s = (lin & 7) * 256 + (lin >> 3);
    bx = s & 31; by = (s >> 5) & 31; bz = s >> 10;
  }
  float* Cout;
  const float* rs = nullptr;
  int m0 = bx * BM;          // column base in A
  int cm0 = m0;              // row base in C
  if (mode == 0) {
    if (bz == 2) {
      if (bx >= 8) return;
      Cout = C0;
    } else {
      if (bx < 8) return;
      Cout = C1 + (size_t)bz * 512 * HW;
      cm0 = (bx - 8) * BM;
    }
  } else {
    Cout = C0 + (size_t)bz * sC;
    rs = rs0 + (size_t)bz * HW;
  }
  const unsigned* Ah = Ah0 + (size_t)bz * sA;
  const unsigned* Al = Al0 + (size_t)bz * sA;
  const unsigned* Bh = Bh0 + (size_t)bz * sB;
  const unsigned* Bl = Bl0 + (size_t)bz * sB;
  int n0 = by * BM;

  __shared__ u32x4 AsV[BM * 8];
  __shared__ u32x4 BsV[BM * 8];
  unsigned* As = (unsigned*)AsV;
  unsigned* Bs = (unsigned*)BsV;

  int tid = threadIdx.x;
  int lane = tid & 63, wave = tid >> 6;
  int wr = wave >> 1, wc = wave & 1;
  int sn = tid & 127, kq = tid >> 7;       // staging: column sn, k-half kq
  int fcol = lane & 15, l16 = lane >> 4;

  f32x4 acc[4][4] = {};
  unsigned rah[8], ral[8], rbh[8], rbl[8];

#define LOADT(KT)                                                         \
  {                                                                       \
    size_t rb_ = (size_t)((KT) * 16 + kq * 8);                            \
    const unsigned* pah = Ah + rb_ * lda + m0 + sn;                       \
    const unsigned* pal = Al + rb_ * lda + m0 + sn;                       \
    const unsigned* pbh = Bh + rb_ * HW + n0 + sn;                        \
    const unsigned* pbl = Bl + rb_ * HW + n0 + sn;                        \
    _Pragma("unroll")                                                     \
    for (int i = 0; i < 8; i++) {                                         \
      rah[i] = pah[(size_t)i * lda];                                      \
      ral[i] = pal[(size_t)i * lda];                                      \
      rbh[i] = pbh[(size_t)i * HW];                                       \
      rbl[i] = pbl[(size_t)i * HW];                                       \
    }                                                                     \
  }

  LOADT(0);

  for (int kt = 0; kt < CH / BK; ++kt) {
    __syncthreads();
    {
      int xa = sn & 7;
      int q0 = ((2 * kq) ^ xa) << 2, q1 = ((2 * kq + 1) ^ xa) << 2;
      int q2 = ((4 + 2 * kq) ^ xa) << 2, q3 = ((5 + 2 * kq) ^ xa) << 2;
      u32x4 w;
      w = u32x4{rah[0], rah[1], rah[2], rah[3]};
      *reinterpret_cast<u32x4*>(&As[sn * 32 + q0]) = w;
      w = u32x4{rah[4], rah[5], rah[6], rah[7]};
      *reinterpret_cast<u32x4*>(&As[sn * 32 + q1]) = w;
      w = u32x4{ral[0], ral[1], ral[2], ral[3]};
      *reinterpret_cast<u32x4*>(&As[sn * 32 + q2]) = w;
      w = u32x4{ral[4], ral[5], ral[6], ral[7]};
      *reinterpret_cast<u32x4*>(&As[sn * 32 + q3]) = w;
      w = u32x4{rbh[0], rbh[1], rbh[2], rbh[3]};
      *reinterpret_cast<u32x4*>(&Bs[sn * 32 + q0]) = w;
      w = u32x4{rbh[4], rbh[5], rbh[6], rbh[7]};
      *reinterpret_cast<u32x4*>(&Bs[sn * 32 + q1]) = w;
      w = u32x4{rbl[0], rbl[1], rbl[2], rbl[3]};
      *reinterpret_cast<u32x4*>(&Bs[sn * 32 + q2]) = w;
      w = u32x4{rbl[4], rbl[5], rbl[6], rbl[7]};
      *reinterpret_cast<u32x4*>(&Bs[sn * 32 + q3]) = w;
    }
    __syncthreads();

    if (kt + 1 < CH / BK) LOADT(kt + 1);   // prefetch hides under MFMA

    short8 bhf[4], blf[4];
#pragma unroll
    for (int nf = 0; nf < 4; nf++) {
      int nloc = wc * 64 + nf * 16 + fcol;
      bhf[nf] = ldfrag(Bs, nloc, l16);
      blf[nf] = ldfrag(Bs, nloc, 4 + l16);
    }
#pragma unroll
    for (int mf = 0; mf < 4; mf++) {
      int mloc = wr * 64 + mf * 16 + fcol;
      short8 ah = ldfrag(As, mloc, l16);
      short8 al = ldfrag(As, mloc, 4 + l16);
#pragma unroll
      for (int nf = 0; nf < 4; nf++) {
        acc[mf][nf] = __builtin_amdgcn_mfma_f32_16x16x32_bf16(ah, bhf[nf], acc[mf][nf], 0, 0, 0);
        acc[mf][nf] = __builtin_amdgcn_mfma_f32_16x16x32_bf16(ah, blf[nf], acc[mf][nf], 0, 0, 0);
        acc[mf][nf] = __builtin_amdgcn_mfma_f32_16x16x32_bf16(al, bhf[nf], acc[mf][nf], 0, 0, 0);
      }
    }
  }
#undef LOADT

  int rbase = l16 * 4;
#pragma unroll
  for (int mf = 0; mf < 4; mf++) {
    int mbase = cm0 + wr * 64 + mf * 16 + rbase;
#pragma unroll
    for (int r = 0; r < 4; r++) {
      float sc = rs ? rs[mbase + r] : 1.0f;
#pragma unroll
      for (int nf = 0; nf < 4; nf++) {
        int n = n0 + wc * 64 + nf * 16 + fcol;
        Cout[(size_t)(mbase + r) * HW + n] = acc[mf][nf][r] * sc;
      }
    }
  }
}

// Partial argmax over hw chunks of 1024; first-occurrence tie-break.
__global__ __launch_bounds__(256) void argmax_part_k(const float* __restrict__ sim,
                                                     float* __restrict__ pmax,
                                                     int* __restrict__ pidx) {
  int s = blockIdx.z, hwc = blockIdx.y, xy0 = blockIdx.x * 64;
  int tid = threadIdx.x, xl = tid & 63, r = tid >> 6;
  const float* base = sim + ((size_t)s * HW + hwc * 1024) * HW + xy0 + xl;
  float bv = -FLT_MAX;
  int bi = 0x7fffffff;
  for (int t = 0; t < 256; t++) {
    int hw = r + 4 * t;
    float v = base[(size_t)hw * HW];
    if (v > bv) { bv = v; bi = hwc * 1024 + hw; }
  }
  __shared__ float sv[256];
  __shared__ int si[256];
  sv[tid] = bv;
  si[tid] = bi;
  __syncthreads();
  if (r == 0) {
    for (int rr = 1; rr < 4; rr++) {
      float v = sv[tid + 64 * rr];
      int i = si[tid + 64 * rr];
      if (v > bv || (v == bv && i < bi)) { bv = v; bi = i; }
    }
    int o = (s * 4 + hwc) * HW + xy0 + xl;
    pmax[o] = bv;
    pidx[o] = bi;
  }
}

__global__ __launch_bounds__(256) void votes_k(const float* __restrict__ pmax,
                                               const int* __restrict__ pidx,
                                               const int* __restrict__ mask,
                                               float* __restrict__ out) {
  int xy = blockIdx.x * 256 + threadIdx.x;
  int vote = 0;
  for (int s = 0; s < SREF; s++) {
    float bv = -FLT_MAX;
    int bi = 0x7fffffff;
    for (int hwc = 0; hwc < 4; hwc++) {
      int o = (s * 4 + hwc) * HW + xy;
      float v = pmax[o];
      int i = pidx[o];
      if (v > bv || (v == bv && i < bi)) { bv = v; bi = i; }
    }
    vote += (mask[s * HW + bi] != 0);
  }
  out[xy] = (float)vote;
}

extern "C" void kernel_launch(void* const* d_in, const int* in_sizes, int n_in,
                              void* d_out, int out_size, void* d_ws, size_t ws_size,
                              hipStream_t stream) {
  const float* fmaps = (const float*)d_in[0];
  const int* mask = (const int*)d_in[1];
  const float* basis = (const float*)d_in[2];
  float* out = (float*)d_out;
  float* ws = (float*)d_ws;

  unsigned* fh = (unsigned*)ws;                       // hi plane, 3 frames
  unsigned* fl = (unsigned*)(ws + 6291456);           // lo plane
  float* invn = ws + 12582912;
  float* invc = ws + 12595200;
  float* counts = ws + 12607488;
  float* protos = ws + 12607552;
  float* protod = ws + 12609600;
  float* proto = ws + 12611648;
  float* pmax = ws + 12612672;
  int* pidx = (int*)(ws + 12645440);

  float* sim = out;
  float* simfwd = out + 33554432;
  float* votes = out + 33558528;
  // out-region scratch (dead before sim GEMM writes):
  unsigned* Ach = (unsigned*)out;                     // 512*1536
  unsigned* Acl = (unsigned*)(out + 786432);
  float* coef = out + 1572864;                        // 2*512*4096
  float* Xd = out + 5767168;                          // 1024*4096

  // 1) fn = l2norm(fmaps, C), split planes (3 frames)
  colnorm_k<<<dim3(TFR * 64), 256, 0, stream>>>(fmaps, invn);
  scale_pack_k<<<dim3(TFR * 2048), 256, 0, stream>>>(fmaps, invn, fh, fl);

  // 2) combined A: projector (cols 0..1023) + padded basis (cols 1024..1535)
  proj_pack_k<<<dim3(16, 16), 256, 0, stream>>>(basis, Ach, Acl);
  pack_basis_k<<<dim3(512), 256, 0, stream>>>(basis, Ach, Acl);

  // 3) one batched dispatch: coef = B^T fn_refs (z<2), Xd = P fn_tgt (z=2)
  gemm3p_k<<<dim3(12, 32, 3), 256, 0, stream>>>(
      Ach, Acl, 1536, 0, fh, fl, (size_t)512 * HW, Xd, 0, coef,
      (const float*)0, 0, 0);
  normref_k<<<dim3(64, 2), 256, 0, stream>>>(coef, invc);

  // 4) tgt renorm + repack into planes frame 2
  colnorm_k<<<dim3(64), 256, 0, stream>>>(Xd, invc + 2 * HW);
  scale_pack_k<<<dim3(2048), 256, 0, stream>>>(
      Xd, invc + 2 * HW, fh + (size_t)2 * 512 * HW, fl + (size_t)2 * 512 * HW);

  // 5) prototype: masked weighted sum -> project -> mean -> normalize
  count_k<<<2, 256, 0, stream>>>(mask, counts);
  proto_k<<<1024, 256, 0, stream>>>(fh, fl, mask, invc, protos);
  protomv_k<<<8, 256, 0, stream>>>(Ach, Acl, protos, protod);
  protonorm_k<<<1, 256, 0, stream>>>(protod, counts, proto);

  // 6) sim_fwd
  simfwd_k<<<64, 256, 0, stream>>>(fh, fl, proto, simfwd);

  // 7) sim = diag(invc_ref) . fn_refs^T @ fd_tgt_deb  (XCD-swizzled)
  gemm3p_k<<<dim3(32, 32, 2), 256, 0, stream>>>(
      fh, fl, HW, (size_t)512 * HW, fh + (size_t)2 * 512 * HW,
      fl + (size_t)2 * 512 * HW, 0, sim, (size_t)HW * HW, (float*)0,
      invc, 1, 1);

  // 8) votes
  argmax_part_k<<<dim3(64, 4, 2), 256, 0, stream>>>(sim, pmax, pidx);
  votes_k<<<16, 256, 0, stream>>>(pmax, pidx, mask, votes);
}

// Round 6
// 667.452 us; speedup vs baseline: 1.0530x; 1.0002x over previous
//
#include <hip/hip_runtime.h>
#include <hip/hip_bf16.h>
#include <cfloat>

#define CH   1024
#define HW   4096
#define NSVD 500
#define TFR  3
#define SREF 2

typedef __attribute__((ext_vector_type(4))) float f32x4;
typedef __attribute__((ext_vector_type(4))) unsigned int u32x4;
typedef __attribute__((ext_vector_type(8))) short short8;

// ---------------------------------------------------------------------------
// Split-bf16 plane format: value x = hi + lo (both bf16). Global planes hold
// channel-PAIRS per u32: H[t][c/2][n] = bf16hi(x[c,n]) | bf16hi(x[c+1,n])<<16.
// ws layout (float units):
//   fh   : 0          (3*512*4096 u32)  hi plane
//   fl   : 6,291,456  (3*512*4096 u32)  lo plane
//   invn : 12,582,912 (3*4096)
//   invc : 12,595,200 (3*4096)  refs: 1/sqrt(1-||coef||^2); tgt: 1/||Xd_t||
//   counts/protos/protod/proto/pmax/pidx follow
// d_out scratch (dead before sim GEMM writes):
//   Acomb_h: 0          (512*1536 u32)  [k-pair][m]: cols 0..1023 = P, 1024.. = basis
//   Acomb_l: 786,432
//   coef   : 1,572,864  (2*512*4096 f32)
//   Xd     : 5,767,168  (1024*4096 f32)
// ---------------------------------------------------------------------------

__device__ inline unsigned bfr(float x) {        // fp32 -> bf16 bits, RNE
  unsigned u = __float_as_uint(x);
  return (u + 0x7fffu + ((u >> 16) & 1u)) >> 16;
}
__device__ inline float lores(float x, unsigned h) {   // residual after hi
  return x - __uint_as_float(h << 16);
}
__device__ inline float vlo(unsigned ph, unsigned pl) {   // value of LOW half-pair
  return __uint_as_float(ph << 16) + __uint_as_float(pl << 16);
}
__device__ inline float vhi(unsigned ph, unsigned pl) {   // value of HIGH half-pair
  return __uint_as_float(ph & 0xFFFF0000u) + __uint_as_float(pl & 0xFFFF0000u);
}

// Column L2 norms over C, layout (t, c, n): inv[t*HW+n] = 1/max(||.||,1e-12)
__global__ __launch_bounds__(256) void colnorm_k(const float* __restrict__ src,
                                                 float* __restrict__ inv) {
  int blk = blockIdx.x;
  int t = blk >> 6;
  int n0 = (blk & 63) * 64;
  int tid = threadIdx.x;
  int nl = tid & 63, r = tid >> 6;
  const float* base = src + (size_t)t * CH * HW + n0 + nl;
  float s = 0.f;
  for (int c = r; c < CH; c += 4) {
    float v = base[(size_t)c * HW];
    s += v * v;
  }
  __shared__ float red[256];
  red[tid] = s;
  __syncthreads();
  if (r == 0) {
    float tot = red[nl] + red[nl + 64] + red[nl + 128] + red[nl + 192];
    inv[t * HW + n0 + nl] = 1.0f / fmaxf(sqrtf(tot), 1e-12f);
  }
}

// planes <- pack(src[t,c,n] * inv[t,n]); thread: one (t, c-pair), 4 n's
__global__ __launch_bounds__(256) void scale_pack_k(const float* __restrict__ src,
                                                    const float* __restrict__ inv,
                                                    unsigned* __restrict__ Hh,
                                                    unsigned* __restrict__ Hl) {
  int gid = blockIdx.x * 256 + threadIdx.x;
  int t = gid >> 19;
  int c2 = (gid >> 10) & 511;
  int n4 = (gid & 1023) << 2;
  const float* r0 = src + ((size_t)t * CH + 2 * c2) * HW + n4;
  float4 v0 = *reinterpret_cast<const float4*>(r0);
  float4 v1 = *reinterpret_cast<const float4*>(r0 + HW);
  float4 w = *reinterpret_cast<const float4*>(inv + t * HW + n4);
  float a0[4] = {v0.x * w.x, v0.y * w.y, v0.z * w.z, v0.w * w.w};
  float a1[4] = {v1.x * w.x, v1.y * w.y, v1.z * w.z, v1.w * w.w};
  u32x4 oh, ol;
#pragma unroll
  for (int i = 0; i < 4; i++) {
    unsigned h0 = bfr(a0[i]), h1 = bfr(a1[i]);
    unsigned l0 = bfr(lores(a0[i], h0)), l1 = bfr(lores(a1[i], h1));
    oh[i] = h0 | (h1 << 16);
    ol[i] = l0 | (l1 << 16);
  }
  size_t o = ((size_t)t * 512 + c2) * HW + n4;
  *reinterpret_cast<u32x4*>(Hh + o) = oh;
  *reinterpret_cast<u32x4*>(Hl + o) = ol;
}

// Acomb cols 0..1023: P = I - basis@basis^T, stored [k/2][m] (uses symmetry)
__global__ __launch_bounds__(256) void proj_pack_k(const float* __restrict__ bas,
                                                   unsigned* __restrict__ Ah,
                                                   unsigned* __restrict__ Al) {
  int m0 = blockIdx.x * 64, n0 = blockIdx.y * 64;
  int tid = threadIdx.x;
  int tx = tid & 15, ty = tid >> 4;
  int lm = tid & 63, lk = tid >> 6;
  __shared__ float As[16][64];
  __shared__ float Bs[16][64];
  float acc[4][4] = {};
  for (int k0 = 0; k0 < 512; k0 += 16) {
#pragma unroll
    for (int i = 0; i < 4; i++) {
      int k = k0 + lk * 4 + i;
      As[lk * 4 + i][lm] = (k < NSVD) ? bas[(size_t)(m0 + lm) * NSVD + k] : 0.f;
      Bs[lk * 4 + i][lm] = (k < NSVD) ? bas[(size_t)(n0 + lm) * NSVD + k] : 0.f;
    }
    __syncthreads();
#pragma unroll
    for (int kk = 0; kk < 16; kk++) {
      float a[4], b[4];
#pragma unroll
      for (int i = 0; i < 4; i++) a[i] = As[kk][ty * 4 + i];
#pragma unroll
      for (int j = 0; j < 4; j++) b[j] = Bs[kk][tx * 4 + j];
#pragma unroll
      for (int i = 0; i < 4; i++)
#pragma unroll
        for (int j = 0; j < 4; j++) acc[i][j] += a[i] * b[j];
    }
    __syncthreads();
  }
  // P[m][n] pairs along n -> Acomb[(n/2)][m]
#pragma unroll
  for (int jp = 0; jp < 2; jp++) {
    u32x4 oh, ol;
#pragma unroll
    for (int i = 0; i < 4; i++) {
      int m = m0 + ty * 4 + i;
      int na = n0 + tx * 4 + 2 * jp, nb = na + 1;
      float va = ((m == na) ? 1.0f : 0.0f) - acc[i][2 * jp];
      float vb = ((m == nb) ? 1.0f : 0.0f) - acc[i][2 * jp + 1];
      unsigned ha = bfr(va), hb = bfr(vb);
      oh[i] = ha | (hb << 16);
      ol[i] = bfr(lores(va, ha)) | (bfr(lores(vb, hb)) << 16);
    }
    size_t r = (size_t)((n0 + tx * 4) / 2 + jp) * 1536 + m0 + ty * 4;
    *reinterpret_cast<u32x4*>(Ah + r) = oh;
    *reinterpret_cast<u32x4*>(Al + r) = ol;
  }
}

// Acomb cols 1024..1535: basis [c][svd] zero-padded to 512, pairs along c
__global__ __launch_bounds__(256) void pack_basis_k(const float* __restrict__ bas,
                                                    unsigned* __restrict__ Ah,
                                                    unsigned* __restrict__ Al) {
  int r = blockIdx.x;            // c-pair
  for (int m = threadIdx.x; m < 512; m += 256) {
    float b0 = (m < NSVD) ? bas[(size_t)(2 * r) * NSVD + m] : 0.f;
    float b1 = (m < NSVD) ? bas[(size_t)(2 * r + 1) * NSVD + m] : 0.f;
    unsigned h0 = bfr(b0), h1 = bfr(b1);
    size_t o = (size_t)r * 1536 + 1024 + m;
    Ah[o] = h0 | (h1 << 16);
    Al[o] = bfr(lores(b0, h0)) | (bfr(lores(b1, h1)) << 16);
  }
}

// invc[s*HW+n] = 1/max(sqrt(max(1 - sum_m coef^2, 0)), 1e-12)
__global__ __launch_bounds__(256) void normref_k(const float* __restrict__ coef,
                                                 float* __restrict__ invc) {
  int s = blockIdx.y;
  int n0 = blockIdx.x * 64;
  int tid = threadIdx.x, nl = tid & 63, r = tid >> 6;
  const float* base = coef + (size_t)s * 512 * HW + n0 + nl;
  float s2 = 0.f;
  for (int m = r; m < 512; m += 4) {
    float v = base[(size_t)m * HW];
    s2 += v * v;
  }
  __shared__ float red[256];
  red[tid] = s2;
  __syncthreads();
  if (r == 0) {
    float tot = red[nl] + red[nl + 64] + red[nl + 128] + red[nl + 192];
    invc[s * HW + n0 + nl] = 1.0f / fmaxf(sqrtf(fmaxf(1.0f - tot, 0.0f)), 1e-12f);
  }
}

__global__ __launch_bounds__(256) void count_k(const int* __restrict__ mask,
                                               float* __restrict__ counts) {
  int s = blockIdx.x;
  int tid = threadIdx.x;
  int c = 0;
  for (int i = tid; i < HW; i += 256) c += (mask[s * HW + i] != 0);
  __shared__ int red[256];
  red[tid] = c;
  __syncthreads();
  for (int o = 128; o > 0; o >>= 1) {
    if (tid < o) red[tid] += red[tid + o];
    __syncthreads();
  }
  if (tid == 0) counts[s] = fmaxf((float)red[0], 1.0f);
}

// protos[s*CH + c] = sum_n mask[s,n] * fn[c,n] * invc[s,n]; block = (s, c-pair)
__global__ __launch_bounds__(256) void proto_k(const unsigned* __restrict__ Hh,
                                               const unsigned* __restrict__ Hl,
                                               const int* __restrict__ mask,
                                               const float* __restrict__ invc,
                                               float* __restrict__ protos) {
  int s = blockIdx.x >> 9, c2 = blockIdx.x & 511;
  int tid = threadIdx.x;
  size_t o = ((size_t)s * 512 + c2) * HW;
  const int* mrow = mask + s * HW;
  const float* wrow = invc + s * HW;
  float a0 = 0.f, a1 = 0.f;
  for (int i = tid; i < HW; i += 256) {
    if (mrow[i]) {
      unsigned h = Hh[o + i], l = Hl[o + i];
      float w = wrow[i];
      a0 += vlo(h, l) * w;
      a1 += vhi(h, l) * w;
    }
  }
  __shared__ float r0[256], r1[256];
  r0[tid] = a0; r1[tid] = a1;
  __syncthreads();
  for (int o2 = 128; o2 > 0; o2 >>= 1) {
    if (tid < o2) { r0[tid] += r0[tid + o2]; r1[tid] += r1[tid + o2]; }
    __syncthreads();
  }
  if (tid == 0) {
    protos[s * CH + 2 * c2] = r0[0];
    protos[s * CH + 2 * c2 + 1] = r1[0];
  }
}

// protod[s*CH+c] = sum_k P[c][k]*protos[s*CH+k]  (P sym; Acomb[k/2][c], lda 1536)
__global__ __launch_bounds__(256) void protomv_k(const unsigned* __restrict__ Ah,
                                                 const unsigned* __restrict__ Al,
                                                 const float* __restrict__ protos,
                                                 float* __restrict__ protod) {
  int s = blockIdx.x >> 2;
  int c = (blockIdx.x & 3) * 256 + threadIdx.x;
  __shared__ float w[CH];
  for (int k = threadIdx.x; k < CH; k += 256) w[k] = protos[s * CH + k];
  __syncthreads();
  float acc = 0.f;
  for (int r = 0; r < 512; r++) {
    unsigned h = Ah[(size_t)r * 1536 + c], l = Al[(size_t)r * 1536 + c];
    acc += vlo(h, l) * w[2 * r] + vhi(h, l) * w[2 * r + 1];
  }
  protod[s * CH + c] = acc;
}

__global__ __launch_bounds__(256) void protonorm_k(const float* __restrict__ protod,
                                                   const float* __restrict__ counts,
                                                   float* __restrict__ proto) {
  int tid = threadIdx.x;
  __shared__ float sm[CH];
  __shared__ float red[256];
  float c0 = counts[0], c1 = counts[1];
  float ss = 0.f;
  for (int c = tid; c < CH; c += 256) {
    float m = 0.5f * (protod[c] / c0 + protod[CH + c] / c1);
    sm[c] = m;
    ss += m * m;
  }
  red[tid] = ss;
  __syncthreads();
  for (int o = 128; o > 0; o >>= 1) {
    if (tid < o) red[tid] += red[tid + o];
    __syncthreads();
  }
  __syncthreads();
  float inv = 1.0f / fmaxf(sqrtf(red[0]), 1e-12f);
  for (int c = tid; c < CH; c += 256) proto[c] = sm[c] * inv;
}

// sim_fwd[n] = sum_c tgt[c][n]*proto[c]; 64 blocks, 4-way c-split
__global__ __launch_bounds__(256) void simfwd_k(const unsigned* __restrict__ Hh,
                                                const unsigned* __restrict__ Hl,
                                                const float* __restrict__ proto,
                                                float* __restrict__ out) {
  __shared__ float p[CH];
  __shared__ float red[256];
  int tid = threadIdx.x;
  for (int c = tid; c < CH; c += 256) p[c] = proto[c];
  __syncthreads();
  int nl = tid & 63, r = tid >> 6;
  int n = blockIdx.x * 64 + nl;
  size_t base = (size_t)(2 * 512) * HW + n;
  float acc = 0.f;
  for (int c2 = r; c2 < 512; c2 += 4) {
    unsigned h = Hh[base + (size_t)c2 * HW], l = Hl[base + (size_t)c2 * HW];
    acc += vlo(h, l) * p[2 * c2] + vhi(h, l) * p[2 * c2 + 1];
  }
  red[tid] = acc;
  __syncthreads();
  if (r == 0) out[n] = red[nl] + red[nl + 64] + red[nl + 128] + red[nl + 192];
}

// ---------------------------------------------------------------------------
// Split-bf16 plane TN GEMM, K=1024: C[m,n] = rs[m]*sum_k A[k][m]*B[k][n].
// LDS row = 128B {hi(32 bf16) | lo(32 bf16)}, 16B quads XOR-swizzled q^(row&7).
// Fragment = one ds_read_b128 (direct short8 MFMA operand). No perms.
// mode 0: batched debias (A=Acomb lda 1536; z<2 & bx>=8 -> coef; z==2 & bx<8 -> Xd)
// mode 1: sim (A=fn frame z, rs=invc row-scale, XCD-swizzled grid)
// ---------------------------------------------------------------------------
#define BM 128
#define BK 32

__device__ __forceinline__ short8 ldfrag(const unsigned* S, int loc, int q) {
  return *reinterpret_cast<const short8*>(&S[loc * 32 + ((q ^ (loc & 7)) << 2)]);
}

__global__ __launch_bounds__(256) void gemm3p_k(
    const unsigned* __restrict__ Ah0, const unsigned* __restrict__ Al0,
    int lda, size_t sA,
    const unsigned* __restrict__ Bh0, const unsigned* __restrict__ Bl0,
    size_t sB,
    float* __restrict__ C0, size_t sC, float* __restrict__ C1,
    const float* __restrict__ rs0, int mode, int swz) {
  int bx = blockIdx.x, by = blockIdx.y, bz = blockIdx.z;
  if (swz) {
    int lin = (bz * 32 + by) * 32 + bx;
    int s = (lin & 7) * 256 + (lin >> 3);
    bx = s & 31; by = (s >> 5) & 31; bz = s >> 10;
  }
  float* Cout;
  const float* rs = nullptr;
  int m0 = bx * BM;          // column base in A
  int cm0 = m0;              // row base in C
  if (mode == 0) {
    if (bz == 2) {
      if (bx >= 8) return;
      Cout = C0;
    } else {
      if (bx < 8) return;
      Cout = C1 + (size_t)bz * 512 * HW;
      cm0 = (bx - 8) * BM;
    }
  } else {
    Cout = C0 + (size_t)bz * sC;
    rs = rs0 + (size_t)bz * HW;
  }
  const unsigned* Ah = Ah0 + (size_t)bz * sA;
  const unsigned* Al = Al0 + (size_t)bz * sA;
  const unsigned* Bh = Bh0 + (size_t)bz * sB;
  const unsigned* Bl = Bl0 + (size_t)bz * sB;
  int n0 = by * BM;

  __shared__ u32x4 AsV[BM * 8];
  __shared__ u32x4 BsV[BM * 8];
  unsigned* As = (unsigned*)AsV;
  unsigned* Bs = (unsigned*)BsV;

  int tid = threadIdx.x;
  int lane = tid & 63, wave = tid >> 6;
  int wr = wave >> 1, wc = wave & 1;
  int sn = tid & 127, kq = tid >> 7;       // staging: column sn, k-half kq
  int fcol = lane & 15, l16 = lane >> 4;

  f32x4 acc[4][4] = {};
  unsigned rah[8], ral[8], rbh[8], rbl[8];

#define LOADT(KT)                                                         \
  {                                                                       \
    size_t rb_ = (size_t)((KT) * 16 + kq * 8);                            \
    const unsigned* pah = Ah + rb_ * lda + m0 + sn;                       \
    const unsigned* pal = Al + rb_ * lda + m0 + sn;                       \
    const unsigned* pbh = Bh + rb_ * HW + n0 + sn;                        \
    const unsigned* pbl = Bl + rb_ * HW + n0 + sn;                        \
    _Pragma("unroll")                                                     \
    for (int i = 0; i < 8; i++) {                                         \
      rah[i] = pah[(size_t)i * lda];                                      \
      ral[i] = pal[(size_t)i * lda];                                      \
      rbh[i] = pbh[(size_t)i * HW];                                       \
      rbl[i] = pbl[(size_t)i * HW];                                       \
    }                                                                     \
  }

  LOADT(0);

  for (int kt = 0; kt < CH / BK; ++kt) {
    __syncthreads();
    {
      int xa = sn & 7;
      int q0 = ((2 * kq) ^ xa) << 2, q1 = ((2 * kq + 1) ^ xa) << 2;
      int q2 = ((4 + 2 * kq) ^ xa) << 2, q3 = ((5 + 2 * kq) ^ xa) << 2;
      u32x4 w;
      w = u32x4{rah[0], rah[1], rah[2], rah[3]};
      *reinterpret_cast<u32x4*>(&As[sn * 32 + q0]) = w;
      w = u32x4{rah[4], rah[5], rah[6], rah[7]};
      *reinterpret_cast<u32x4*>(&As[sn * 32 + q1]) = w;
      w = u32x4{ral[0], ral[1], ral[2], ral[3]};
      *reinterpret_cast<u32x4*>(&As[sn * 32 + q2]) = w;
      w = u32x4{ral[4], ral[5], ral[6], ral[7]};
      *reinterpret_cast<u32x4*>(&As[sn * 32 + q3]) = w;
      w = u32x4{rbh[0], rbh[1], rbh[2], rbh[3]};
      *reinterpret_cast<u32x4*>(&Bs[sn * 32 + q0]) = w;
      w = u32x4{rbh[4], rbh[5], rbh[6], rbh[7]};
      *reinterpret_cast<u32x4*>(&Bs[sn * 32 + q1]) = w;
      w = u32x4{rbl[0], rbl[1], rbl[2], rbl[3]};
      *reinterpret_cast<u32x4*>(&Bs[sn * 32 + q2]) = w;
      w = u32x4{rbl[4], rbl[5], rbl[6], rbl[7]};
      *reinterpret_cast<u32x4*>(&Bs[sn * 32 + q3]) = w;
    }
    __syncthreads();

    if (kt + 1 < CH / BK) LOADT(kt + 1);   // prefetch hides under MFMA

    short8 bhf[4], blf[4];
#pragma unroll
    for (int nf = 0; nf < 4; nf++) {
      int nloc = wc * 64 + nf * 16 + fcol;
      bhf[nf] = ldfrag(Bs, nloc, l16);
      blf[nf] = ldfrag(Bs, nloc, 4 + l16);
    }
#pragma unroll
    for (int mf = 0; mf < 4; mf++) {
      int mloc = wr * 64 + mf * 16 + fcol;
      short8 ah = ldfrag(As, mloc, l16);
      short8 al = ldfrag(As, mloc, 4 + l16);
#pragma unroll
      for (int nf = 0; nf < 4; nf++) {
        acc[mf][nf] = __builtin_amdgcn_mfma_f32_16x16x32_bf16(ah, bhf[nf], acc[mf][nf], 0, 0, 0);
        acc[mf][nf] = __builtin_amdgcn_mfma_f32_16x16x32_bf16(ah, blf[nf], acc[mf][nf], 0, 0, 0);
        acc[mf][nf] = __builtin_amdgcn_mfma_f32_16x16x32_bf16(al, bhf[nf], acc[mf][nf], 0, 0, 0);
      }
    }
  }
#undef LOADT

  int rbase = l16 * 4;
#pragma unroll
  for (int mf = 0; mf < 4; mf++) {
    int mbase = cm0 + wr * 64 + mf * 16 + rbase;
#pragma unroll
    for (int r = 0; r < 4; r++) {
      float sc = rs ? rs[mbase + r] : 1.0f;
#pragma unroll
      for (int nf = 0; nf < 4; nf++) {
        int n = n0 + wc * 64 + nf * 16 + fcol;
        Cout[(size_t)(mbase + r) * HW + n] = acc[mf][nf][r] * sc;
      }
    }
  }
}

// Partial argmax over hw chunks of 1024; first-occurrence tie-break.
__global__ __launch_bounds__(256) void argmax_part_k(const float* __restrict__ sim,
                                                     float* __restrict__ pmax,
                                                     int* __restrict__ pidx) {
  int s = blockIdx.z, hwc = blockIdx.y, xy0 = blockIdx.x * 64;
  int tid = threadIdx.x, xl = tid & 63, r = tid >> 6;
  const float* base = sim + ((size_t)s * HW + hwc * 1024) * HW + xy0 + xl;
  float bv = -FLT_MAX;
  int bi = 0x7fffffff;
  for (int t = 0; t < 256; t++) {
    int hw = r + 4 * t;
    float v = base[(size_t)hw * HW];
    if (v > bv) { bv = v; bi = hwc * 1024 + hw; }
  }
  __shared__ float sv[256];
  __shared__ int si[256];
  sv[tid] = bv;
  si[tid] = bi;
  __syncthreads();
  if (r == 0) {
    for (int rr = 1; rr < 4; rr++) {
      float v = sv[tid + 64 * rr];
      int i = si[tid + 64 * rr];
      if (v > bv || (v == bv && i < bi)) { bv = v; bi = i; }
    }
    int o = (s * 4 + hwc) * HW + xy0 + xl;
    pmax[o] = bv;
    pidx[o] = bi;
  }
}

__global__ __launch_bounds__(256) void votes_k(const float* __restrict__ pmax,
                                               const int* __restrict__ pidx,
                                               const int* __restrict__ mask,
                                               float* __restrict__ out) {
  int xy = blockIdx.x * 256 + threadIdx.x;
  int vote = 0;
  for (int s = 0; s < SREF; s++) {
    float bv = -FLT_MAX;
    int bi = 0x7fffffff;
    for (int hwc = 0; hwc < 4; hwc++) {
      int o = (s * 4 + hwc) * HW + xy;
      float v = pmax[o];
      int i = pidx[o];
      if (v > bv || (v == bv && i < bi)) { bv = v; bi = i; }
    }
    vote += (mask[s * HW + bi] != 0);
  }
  out[xy] = (float)vote;
}

extern "C" void kernel_launch(void* const* d_in, const int* in_sizes, int n_in,
                              void* d_out, int out_size, void* d_ws, size_t ws_size,
                              hipStream_t stream) {
  const float* fmaps = (const float*)d_in[0];
  const int* mask = (const int*)d_in[1];
  const float* basis = (const float*)d_in[2];
  float* out = (float*)d_out;
  float* ws = (float*)d_ws;

  unsigned* fh = (unsigned*)ws;                       // hi plane, 3 frames
  unsigned* fl = (unsigned*)(ws + 6291456);           // lo plane
  float* invn = ws + 12582912;
  float* invc = ws + 12595200;
  float* counts = ws + 12607488;
  float* protos = ws + 12607552;
  float* protod = ws + 12609600;
  float* proto = ws + 12611648;
  float* pmax = ws + 12612672;
  int* pidx = (int*)(ws + 12645440);

  float* sim = out;
  float* simfwd = out + 33554432;
  float* votes = out + 33558528;
  // out-region scratch (dead before sim GEMM writes):
  unsigned* Ach = (unsigned*)out;                     // 512*1536
  unsigned* Acl = (unsigned*)(out + 786432);
  float* coef = out + 1572864;                        // 2*512*4096
  float* Xd = out + 5767168;                          // 1024*4096

  // 1) fn = l2norm(fmaps, C), split planes (3 frames)
  colnorm_k<<<dim3(TFR * 64), 256, 0, stream>>>(fmaps, invn);
  scale_pack_k<<<dim3(TFR * 2048), 256, 0, stream>>>(fmaps, invn, fh, fl);

  // 2) combined A: projector (cols 0..1023) + padded basis (cols 1024..1535)
  proj_pack_k<<<dim3(16, 16), 256, 0, stream>>>(basis, Ach, Acl);
  pack_basis_k<<<dim3(512), 256, 0, stream>>>(basis, Ach, Acl);

  // 3) one batched dispatch: coef = B^T fn_refs (z<2), Xd = P fn_tgt (z=2)
  gemm3p_k<<<dim3(12, 32, 3), 256, 0, stream>>>(
      Ach, Acl, 1536, 0, fh, fl, (size_t)512 * HW, Xd, 0, coef,
      (const float*)0, 0, 0);
  normref_k<<<dim3(64, 2), 256, 0, stream>>>(coef, invc);

  // 4) tgt renorm + repack into planes frame 2
  colnorm_k<<<dim3(64), 256, 0, stream>>>(Xd, invc + 2 * HW);
  scale_pack_k<<<dim3(2048), 256, 0, stream>>>(
      Xd, invc + 2 * HW, fh + (size_t)2 * 512 * HW, fl + (size_t)2 * 512 * HW);

  // 5) prototype: masked weighted sum -> project -> mean -> normalize
  count_k<<<2, 256, 0, stream>>>(mask, counts);
  proto_k<<<1024, 256, 0, stream>>>(fh, fl, mask, invc, protos);
  protomv_k<<<8, 256, 0, stream>>>(Ach, Acl, protos, protod);
  protonorm_k<<<1, 256, 0, stream>>>(protod, counts, proto);

  // 6) sim_fwd
  simfwd_k<<<64, 256, 0, stream>>>(fh, fl, proto, simfwd);

  // 7) sim = diag(invc_ref) . fn_refs^T @ fd_tgt_deb  (XCD-swizzled)
  gemm3p_k<<<dim3(32, 32, 2), 256, 0, stream>>>(
      fh, fl, HW, (size_t)512 * HW, fh + (size_t)2 * 512 * HW,
      fl + (size_t)2 * 512 * HW, 0, sim, (size_t)HW * HW, (float*)0,
      invc, 1, 1);

  // 8) votes
  argmax_part_k<<<dim3(64, 4, 2), 256, 0, stream>>>(sim, pmax, pidx);
  votes_k<<<16, 256, 0, stream>>>(pmax, pidx, mask, votes);
}

// Round 7
// 612.515 us; speedup vs baseline: 1.1474x; 1.0897x over previous
//
#include <hip/hip_runtime.h>
#include <hip/hip_bf16.h>
#include <cfloat>

#define CH   1024
#define HW   4096
#define NSVD 500
#define TFR  3
#define SREF 2

typedef __attribute__((ext_vector_type(4))) float f32x4;
typedef __attribute__((ext_vector_type(4))) unsigned int u32x4;
typedef __attribute__((ext_vector_type(8))) short short8;

// ---------------------------------------------------------------------------
// Split-bf16 planes in BLOCKED layout (gload_lds-friendly):
//   plane[t][cb][kgrp][cl][kp4] u32, cb = col/256 (16/frame), kgrp = kpair/4
//   (128), cl = col%256, kp4 = kpair%4. u32 (kpair r, col n) holds bf16 of
//   channels 2r (lo16) and 2r+1 (hi16). Frame = 2,097,152 u32 (8 MB).
//   A K-tile slab (4 kgrp x 256 cl x 16B = 16 KB) is CONTIGUOUS.
// Acomb (debias A): same blocked scheme, 6 col-blocks (1536 cols):
//   cols 0..1023 = P = I - B B^T (symmetric), cols 1024..1535 = basis padded.
// ws (float units): fh 0 / fl 6,291,456 / invn 12,582,912 / invc 12,595,200 /
//   counts 12,607,488 / protos 12,607,552 / protod 12,609,600 /
//   proto 12,611,648 / pmax 12,612,672 / pidx 12,645,440
// d_out scratch (dead before simg_k writes): Ach 0, Acl 786,432,
//   coef 1,572,864 (2*512*HW f32), Xd 5,767,168 (1024*HW f32)
// ---------------------------------------------------------------------------

__device__ inline unsigned bfr(float x) {        // fp32 -> bf16 bits, RNE
  unsigned u = __float_as_uint(x);
  return (u + 0x7fffu + ((u >> 16) & 1u)) >> 16;
}
__device__ inline float lores(float x, unsigned h) {
  return x - __uint_as_float(h << 16);
}
__device__ inline float vlo(unsigned ph, unsigned pl) {
  return __uint_as_float(ph << 16) + __uint_as_float(pl << 16);
}
__device__ inline float vhi(unsigned ph, unsigned pl) {
  return __uint_as_float(ph & 0xFFFF0000u) + __uint_as_float(pl & 0xFFFF0000u);
}

// Column L2 norms over C, layout (t, c, n)
__global__ __launch_bounds__(256) void colnorm_k(const float* __restrict__ src,
                                                 float* __restrict__ inv) {
  int blk = blockIdx.x;
  int t = blk >> 6;
  int n0 = (blk & 63) * 64;
  int tid = threadIdx.x;
  int nl = tid & 63, r = tid >> 6;
  const float* base = src + (size_t)t * CH * HW + n0 + nl;
  float s = 0.f;
  for (int c = r; c < CH; c += 4) {
    float v = base[(size_t)c * HW];
    s += v * v;
  }
  __shared__ float red[256];
  red[tid] = s;
  __syncthreads();
  if (r == 0) {
    float tot = red[nl] + red[nl + 64] + red[nl + 128] + red[nl + 192];
    inv[t * HW + n0 + nl] = 1.0f / fmaxf(sqrtf(tot), 1e-12f);
  }
}

// blocked planes <- pack(src[t,c,n]*inv[t,n]); thread owns (t, kgrp, n)
__global__ __launch_bounds__(256) void scale_pack_k(const float* __restrict__ src,
                                                    const float* __restrict__ inv,
                                                    unsigned* __restrict__ Gh,
                                                    unsigned* __restrict__ Gl) {
  int gid = blockIdx.x * 256 + threadIdx.x;
  int lt = gid >> 19;
  int kg = (gid >> 12) & 127;
  int n = gid & 4095;
  const float* s0 = src + ((size_t)lt * CH + kg * 8) * HW + n;
  float w = inv[lt * HW + n];
  unsigned oh[4], ol[4];
#pragma unroll
  for (int j = 0; j < 4; j++) {
    float a = s0[(size_t)(2 * j) * HW] * w;
    float b = s0[(size_t)(2 * j + 1) * HW] * w;
    unsigned ha = bfr(a), hb = bfr(b);
    oh[j] = ha | (hb << 16);
    ol[j] = bfr(lores(a, ha)) | (bfr(lores(b, hb)) << 16);
  }
  size_t vi = (((size_t)lt * 16 + (n >> 8)) * 128 + kg) * 256 + (n & 255);
  *reinterpret_cast<u32x4*>(Gh + vi * 4) = *reinterpret_cast<u32x4*>(oh);
  *reinterpret_cast<u32x4*>(Gl + vi * 4) = *reinterpret_cast<u32x4*>(ol);
}

// Acomb cols 0..1023: P = I - basis@basis^T, blocked write
__global__ __launch_bounds__(256) void proj_pack_k(const float* __restrict__ bas,
                                                   unsigned* __restrict__ Ah,
                                                   unsigned* __restrict__ Al) {
  int m0 = blockIdx.x * 64, n0 = blockIdx.y * 64;
  int tid = threadIdx.x;
  int tx = tid & 15, ty = tid >> 4;
  int lm = tid & 63, lk = tid >> 6;
  __shared__ float As[16][64];
  __shared__ float Bs[16][64];
  float acc[4][4] = {};
  for (int k0 = 0; k0 < 512; k0 += 16) {
#pragma unroll
    for (int i = 0; i < 4; i++) {
      int k = k0 + lk * 4 + i;
      As[lk * 4 + i][lm] = (k < NSVD) ? bas[(size_t)(m0 + lm) * NSVD + k] : 0.f;
      Bs[lk * 4 + i][lm] = (k < NSVD) ? bas[(size_t)(n0 + lm) * NSVD + k] : 0.f;
    }
    __syncthreads();
#pragma unroll
    for (int kk = 0; kk < 16; kk++) {
      float a[4], b[4];
#pragma unroll
      for (int i = 0; i < 4; i++) a[i] = As[kk][ty * 4 + i];
#pragma unroll
      for (int j = 0; j < 4; j++) b[j] = Bs[kk][tx * 4 + j];
#pragma unroll
      for (int i = 0; i < 4; i++)
#pragma unroll
        for (int j = 0; j < 4; j++) acc[i][j] += a[i] * b[j];
    }
    __syncthreads();
  }
#pragma unroll
  for (int jp = 0; jp < 2; jp++) {
    int r = n0 / 2 + tx * 2 + jp;     // kpair
#pragma unroll
    for (int i = 0; i < 4; i++) {
      int c = m0 + ty * 4 + i;        // column
      float va = ((c == 2 * r) ? 1.0f : 0.0f) - acc[i][2 * jp];
      float vb = ((c == 2 * r + 1) ? 1.0f : 0.0f) - acc[i][2 * jp + 1];
      unsigned ha = bfr(va), hb = bfr(vb);
      size_t vi = ((size_t)((c >> 8) * 128 + (r >> 2)) * 256 + (c & 255)) * 4 + (r & 3);
      Ah[vi] = ha | (hb << 16);
      Al[vi] = bfr(lores(va, ha)) | (bfr(lores(vb, hb)) << 16);
    }
  }
}

// Acomb cols 1024..1535: basis zero-padded to 512 svd rows
__global__ __launch_bounds__(256) void pack_basis_k(const float* __restrict__ bas,
                                                    unsigned* __restrict__ Ah,
                                                    unsigned* __restrict__ Al) {
  int r = blockIdx.x;                 // kpair = channel pair
  for (int m = threadIdx.x; m < 512; m += 256) {
    float b0 = (m < NSVD) ? bas[(size_t)(2 * r) * NSVD + m] : 0.f;
    float b1 = (m < NSVD) ? bas[(size_t)(2 * r + 1) * NSVD + m] : 0.f;
    unsigned h0 = bfr(b0), h1 = bfr(b1);
    int c = 1024 + m;
    size_t vi = ((size_t)((c >> 8) * 128 + (r >> 2)) * 256 + (c & 255)) * 4 + (r & 3);
    Ah[vi] = h0 | (h1 << 16);
    Al[vi] = bfr(lores(b0, h0)) | (bfr(lores(b1, h1)) << 16);
  }
}

// invc[s*HW+n] = 1/sqrt(max(1 - sum coef^2, 0))
__global__ __launch_bounds__(256) void normref_k(const float* __restrict__ coef,
                                                 float* __restrict__ invc) {
  int s = blockIdx.y;
  int n0 = blockIdx.x * 64;
  int tid = threadIdx.x, nl = tid & 63, r = tid >> 6;
  const float* base = coef + (size_t)s * 512 * HW + n0 + nl;
  float s2 = 0.f;
  for (int m = r; m < 512; m += 4) {
    float v = base[(size_t)m * HW];
    s2 += v * v;
  }
  __shared__ float red[256];
  red[tid] = s2;
  __syncthreads();
  if (r == 0) {
    float tot = red[nl] + red[nl + 64] + red[nl + 128] + red[nl + 192];
    invc[s * HW + n0 + nl] = 1.0f / fmaxf(sqrtf(fmaxf(1.0f - tot, 0.0f)), 1e-12f);
  }
}

__global__ __launch_bounds__(256) void count_k(const int* __restrict__ mask,
                                               float* __restrict__ counts) {
  int s = blockIdx.x;
  int tid = threadIdx.x;
  int c = 0;
  for (int i = tid; i < HW; i += 256) c += (mask[s * HW + i] != 0);
  __shared__ int red[256];
  red[tid] = c;
  __syncthreads();
  for (int o = 128; o > 0; o >>= 1) {
    if (tid < o) red[tid] += red[tid + o];
    __syncthreads();
  }
  if (tid == 0) counts[s] = fmaxf((float)red[0], 1.0f);
}

// protos[s*CH+c] = sum_n mask*fn*invc; block = (s, kgrp of 8 channels)
__global__ __launch_bounds__(256) void proto_k(const unsigned* __restrict__ Gh,
                                               const unsigned* __restrict__ Gl,
                                               const int* __restrict__ mask,
                                               const float* __restrict__ invc,
                                               float* __restrict__ protos) {
  int s = blockIdx.x >> 7, kg = blockIdx.x & 127;
  int tid = threadIdx.x;
  const u32x4* Hv = (const u32x4*)Gh + (size_t)s * 524288;
  const u32x4* Lv = (const u32x4*)Gl + (size_t)s * 524288;
  float a[8] = {};
  for (int n = tid; n < HW; n += 256) {
    if (mask[s * HW + n]) {
      float w = invc[s * HW + n];
      size_t vi = ((size_t)(n >> 8) * 128 + kg) * 256 + (n & 255);
      u32x4 h = Hv[vi], l = Lv[vi];
#pragma unroll
      for (int j = 0; j < 4; j++) {
        a[2 * j] += vlo(h[j], l[j]) * w;
        a[2 * j + 1] += vhi(h[j], l[j]) * w;
      }
    }
  }
  __shared__ float red[256];
  for (int e = 0; e < 8; e++) {
    red[tid] = a[e];
    __syncthreads();
    for (int o = 128; o > 0; o >>= 1) {
      if (tid < o) red[tid] += red[tid + o];
      __syncthreads();
    }
    if (tid == 0) protos[s * CH + kg * 8 + e] = red[0];
    __syncthreads();
  }
}

// protod[s*CH+c] = sum_k P[c][k]*protos[s][k]  (blocked Acomb, symmetric P)
__global__ __launch_bounds__(256) void protomv_k(const unsigned* __restrict__ Ah,
                                                 const unsigned* __restrict__ Al,
                                                 const float* __restrict__ protos,
                                                 float* __restrict__ protod) {
  int s = blockIdx.x >> 2;
  int c = (blockIdx.x & 3) * 256 + threadIdx.x;
  __shared__ float w[CH];
  for (int k = threadIdx.x; k < CH; k += 256) w[k] = protos[s * CH + k];
  __syncthreads();
  float acc = 0.f;
  for (int r = 0; r < 512; r++) {
    size_t vi = ((size_t)((c >> 8) * 128 + (r >> 2)) * 256 + (c & 255)) * 4 + (r & 3);
    unsigned h = Ah[vi], l = Al[vi];
    acc += vlo(h, l) * w[2 * r] + vhi(h, l) * w[2 * r + 1];
  }
  protod[s * CH + c] = acc;
}

__global__ __launch_bounds__(256) void protonorm_k(const float* __restrict__ protod,
                                                   const float* __restrict__ counts,
                                                   float* __restrict__ proto) {
  int tid = threadIdx.x;
  __shared__ float sm[CH];
  __shared__ float red[256];
  float c0 = counts[0], c1 = counts[1];
  float ss = 0.f;
  for (int c = tid; c < CH; c += 256) {
    float m = 0.5f * (protod[c] / c0 + protod[CH + c] / c1);
    sm[c] = m;
    ss += m * m;
  }
  red[tid] = ss;
  __syncthreads();
  for (int o = 128; o > 0; o >>= 1) {
    if (tid < o) red[tid] += red[tid + o];
    __syncthreads();
  }
  __syncthreads();
  float inv = 1.0f / fmaxf(sqrtf(red[0]), 1e-12f);
  for (int c = tid; c < CH; c += 256) proto[c] = sm[c] * inv;
}

__global__ __launch_bounds__(256) void simfwd_k(const unsigned* __restrict__ Gh,
                                                const unsigned* __restrict__ Gl,
                                                const float* __restrict__ proto,
                                                float* __restrict__ out) {
  __shared__ float p[CH];
  int tid = threadIdx.x;
  for (int c = tid; c < CH; c += 256) p[c] = proto[c];
  __syncthreads();
  int n = blockIdx.x * 256 + tid;
  const u32x4* Hv = (const u32x4*)Gh + (size_t)2 * 524288;
  const u32x4* Lv = (const u32x4*)Gl + (size_t)2 * 524288;
  float acc = 0.f;
  for (int kg = 0; kg < 128; kg++) {
    size_t vi = ((size_t)(n >> 8) * 128 + kg) * 256 + (n & 255);
    u32x4 h = Hv[vi], l = Lv[vi];
#pragma unroll
    for (int j = 0; j < 4; j++)
      acc += vlo(h[j], l[j]) * p[8 * kg + 2 * j] + vhi(h[j], l[j]) * p[8 * kg + 2 * j + 1];
  }
  out[n] = acc;
}

// ---------------------------------------------------------------------------
// Debias GEMM (2-phase 128² kernel, blocked-layout loads).
// out[m,n] = sum_k A[k][m]*B[k][n]; z==2 & bx<8 -> Xd (P part), z<2 & bx>=8
// -> coef (basis part, cols 1024..1535).
// ---------------------------------------------------------------------------
#define BM 128
#define BK 32

__device__ __forceinline__ short8 ldfrag(const unsigned* S, int loc, int q) {
  return *reinterpret_cast<const short8*>(&S[loc * 32 + ((q ^ (loc & 7)) << 2)]);
}

__global__ __launch_bounds__(256) void gemm3d_k(
    const unsigned* __restrict__ Ach, const unsigned* __restrict__ Acl,
    const unsigned* __restrict__ fh, const unsigned* __restrict__ fl,
    float* __restrict__ Xd, float* __restrict__ coef) {
  int bx = blockIdx.x, bz = blockIdx.z;
  float* Cout;
  int m0 = bx * BM, cm0 = m0;
  if (bz == 2) {
    if (bx >= 8) return;
    Cout = Xd;
  } else {
    if (bx < 8) return;
    Cout = coef + (size_t)bz * 512 * HW;
    cm0 = (bx - 8) * BM;
  }
  int n0 = blockIdx.y * BM;
  const u32x4* Ahv = (const u32x4*)Ach;
  const u32x4* Alv = (const u32x4*)Acl;
  const u32x4* Bhv = (const u32x4*)fh + (size_t)bz * 524288;
  const u32x4* Blv = (const u32x4*)fl + (size_t)bz * 524288;

  __shared__ u32x4 AsV[BM * 8];
  __shared__ u32x4 BsV[BM * 8];
  unsigned* As = (unsigned*)AsV;
  unsigned* Bs = (unsigned*)BsV;

  int tid = threadIdx.x;
  int lane = tid & 63, wave = tid >> 6;
  int wr = wave >> 1, wc = wave & 1;
  int sn = tid & 127, kq = tid >> 7;
  int fcol = lane & 15, l16 = lane >> 4;

  int colA = m0 + sn, colB = n0 + sn;
  size_t ia = (size_t)(colA >> 8) * 32768 + (colA & 255);
  size_t ib = (size_t)(colB >> 8) * 32768 + (colB & 255);

  f32x4 acc[4][4] = {};
  unsigned rah[8], ral[8], rbh[8], rbl[8];

#define LOADT(KT)                                                        \
  {                                                                      \
    int g0 = (KT) * 4 + kq * 2;                                          \
    *reinterpret_cast<u32x4*>(&rah[0]) = Ahv[ia + (size_t)g0 * 256];     \
    *reinterpret_cast<u32x4*>(&rah[4]) = Ahv[ia + (size_t)(g0 + 1) * 256]; \
    *reinterpret_cast<u32x4*>(&ral[0]) = Alv[ia + (size_t)g0 * 256];     \
    *reinterpret_cast<u32x4*>(&ral[4]) = Alv[ia + (size_t)(g0 + 1) * 256]; \
    *reinterpret_cast<u32x4*>(&rbh[0]) = Bhv[ib + (size_t)g0 * 256];     \
    *reinterpret_cast<u32x4*>(&rbh[4]) = Bhv[ib + (size_t)(g0 + 1) * 256]; \
    *reinterpret_cast<u32x4*>(&rbl[0]) = Blv[ib + (size_t)g0 * 256];     \
    *reinterpret_cast<u32x4*>(&rbl[4]) = Blv[ib + (size_t)(g0 + 1) * 256]; \
  }

  LOADT(0);

  for (int kt = 0; kt < CH / BK; ++kt) {
    __syncthreads();
    {
      int xa = sn & 7;
      int q0 = ((2 * kq) ^ xa) << 2, q1 = ((2 * kq + 1) ^ xa) << 2;
      int q2 = ((4 + 2 * kq) ^ xa) << 2, q3 = ((5 + 2 * kq) ^ xa) << 2;
      *reinterpret_cast<u32x4*>(&As[sn * 32 + q0]) = *reinterpret_cast<u32x4*>(&rah[0]);
      *reinterpret_cast<u32x4*>(&As[sn * 32 + q1]) = *reinterpret_cast<u32x4*>(&rah[4]);
      *reinterpret_cast<u32x4*>(&As[sn * 32 + q2]) = *reinterpret_cast<u32x4*>(&ral[0]);
      *reinterpret_cast<u32x4*>(&As[sn * 32 + q3]) = *reinterpret_cast<u32x4*>(&ral[4]);
      *reinterpret_cast<u32x4*>(&Bs[sn * 32 + q0]) = *reinterpret_cast<u32x4*>(&rbh[0]);
      *reinterpret_cast<u32x4*>(&Bs[sn * 32 + q1]) = *reinterpret_cast<u32x4*>(&rbh[4]);
      *reinterpret_cast<u32x4*>(&Bs[sn * 32 + q2]) = *reinterpret_cast<u32x4*>(&rbl[0]);
      *reinterpret_cast<u32x4*>(&Bs[sn * 32 + q3]) = *reinterpret_cast<u32x4*>(&rbl[4]);
    }
    __syncthreads();

    if (kt + 1 < CH / BK) LOADT(kt + 1);

    short8 bhf[4], blf[4];
#pragma unroll
    for (int nf = 0; nf < 4; nf++) {
      int nloc = wc * 64 + nf * 16 + fcol;
      bhf[nf] = ldfrag(Bs, nloc, l16);
      blf[nf] = ldfrag(Bs, nloc, 4 + l16);
    }
#pragma unroll
    for (int mf = 0; mf < 4; mf++) {
      int mloc = wr * 64 + mf * 16 + fcol;
      short8 ah = ldfrag(As, mloc, l16);
      short8 al = ldfrag(As, mloc, 4 + l16);
#pragma unroll
      for (int nf = 0; nf < 4; nf++) {
        acc[mf][nf] = __builtin_amdgcn_mfma_f32_16x16x32_bf16(ah, bhf[nf], acc[mf][nf], 0, 0, 0);
        acc[mf][nf] = __builtin_amdgcn_mfma_f32_16x16x32_bf16(ah, blf[nf], acc[mf][nf], 0, 0, 0);
        acc[mf][nf] = __builtin_amdgcn_mfma_f32_16x16x32_bf16(al, bhf[nf], acc[mf][nf], 0, 0, 0);
      }
    }
  }
#undef LOADT

  int rbase = l16 * 4;
#pragma unroll
  for (int mf = 0; mf < 4; mf++) {
    int mbase = cm0 + wr * 64 + mf * 16 + rbase;
#pragma unroll
    for (int r = 0; r < 4; r++) {
#pragma unroll
      for (int nf = 0; nf < 4; nf++) {
        int n = n0 + wc * 64 + nf * 16 + fcol;
        Cout[(size_t)(mbase + r) * HW + n] = acc[mf][nf][r];
      }
    }
  }
}

// ---------------------------------------------------------------------------
// sim GEMM: 256x256 tile, 8 waves (2x4), K-tile=32 elems, gload_lds staging,
// double-buffered 128 KB LDS, counted vmcnt, raw barriers, setprio.
// sim[z][m][n] = invc[z][m] * sum_k fn_ref[z][k][m] * fd_tgt[k][n]
// ---------------------------------------------------------------------------
#define SIMG_NT 32

__global__ __launch_bounds__(512, 2) void simg_k(
    const unsigned* __restrict__ Gh, const unsigned* __restrict__ Gl,
    const float* __restrict__ invc, float* __restrict__ simout) {
  __shared__ __align__(16) unsigned smem[32768];   // 128 KB, 2 x 64 KB bufs

  int orig = (blockIdx.z * 16 + blockIdx.y) * 16 + blockIdx.x;
  int lin = (orig & 7) * 64 + (orig >> 3);         // XCD-contiguous, bijective
  int z = lin >> 8, bx = (lin >> 4) & 15, by = lin & 15;

  const unsigned* srcs[4];
  srcs[0] = Gh + (size_t)z * 2097152 + (size_t)bx * 131072;   // Ah
  srcs[1] = Gl + (size_t)z * 2097152 + (size_t)bx * 131072;   // Al
  srcs[2] = Gh + (size_t)2 * 2097152 + (size_t)by * 131072;   // Bh
  srcs[3] = Gl + (size_t)2 * 2097152 + (size_t)by * 131072;   // Bl

  int tid = threadIdx.x, ln = tid & 63, wv = tid >> 6;
  int wr = wv >> 2, wc = wv & 3;
  int fcol = ln & 15, l16 = ln >> 4;

  f32x4 acc[8][4] = {};

#define STAGE(BSEL, T)                                                        \
  {                                                                           \
    _Pragma("unroll")                                                         \
    for (int op = 0; op < 4; op++) {                                          \
      const unsigned* gs = srcs[op] + (size_t)(T) * 4096;                     \
      _Pragma("unroll")                                                       \
      for (int rr = 0; rr < 2; rr++) {                                        \
        int slot = rr * 512 + wv * 64;                                        \
        __builtin_amdgcn_global_load_lds(                                     \
            (const __attribute__((address_space(1))) unsigned*)(gs + (size_t)(slot + ln) * 4), \
            (__attribute__((address_space(3))) unsigned*)(smem + (BSEL) * 16384 + op * 4096 + slot * 4), \
            16, 0, 0);                                                        \
      }                                                                       \
    }                                                                         \
  }

  STAGE(0, 0);
  STAGE(1, 1);
  asm volatile("s_waitcnt vmcnt(8)" ::: "memory");
  __builtin_amdgcn_s_barrier();
  __builtin_amdgcn_sched_barrier(0);

  for (int t = 0; t < SIMG_NT; ++t) {
    const unsigned* Sb = smem + (t & 1) * 16384;
    short8 bh[4], bl[4];
#pragma unroll
    for (int nf = 0; nf < 4; nf++) {
      int nloc = wc * 64 + nf * 16 + fcol;
      bh[nf] = *reinterpret_cast<const short8*>(Sb + 2 * 4096 + l16 * 1024 + nloc * 4);
      bl[nf] = *reinterpret_cast<const short8*>(Sb + 3 * 4096 + l16 * 1024 + nloc * 4);
    }
    __builtin_amdgcn_s_setprio(1);
#pragma unroll
    for (int mf = 0; mf < 8; mf++) {
      int mloc = wr * 128 + mf * 16 + fcol;
      short8 ah = *reinterpret_cast<const short8*>(Sb + l16 * 1024 + mloc * 4);
      short8 al = *reinterpret_cast<const short8*>(Sb + 4096 + l16 * 1024 + mloc * 4);
#pragma unroll
      for (int nf = 0; nf < 4; nf++) {
        acc[mf][nf] = __builtin_amdgcn_mfma_f32_16x16x32_bf16(ah, bh[nf], acc[mf][nf], 0, 0, 0);
        acc[mf][nf] = __builtin_amdgcn_mfma_f32_16x16x32_bf16(ah, bl[nf], acc[mf][nf], 0, 0, 0);
        acc[mf][nf] = __builtin_amdgcn_mfma_f32_16x16x32_bf16(al, bh[nf], acc[mf][nf], 0, 0, 0);
      }
    }
    __builtin_amdgcn_s_setprio(0);
    asm volatile("s_waitcnt lgkmcnt(0)" ::: "memory");
    __builtin_amdgcn_s_barrier();        // all waves done reading buf[t&1]
    __builtin_amdgcn_sched_barrier(0);
    if (t + 2 < SIMG_NT) {
      STAGE(t & 1, t + 2);
      asm volatile("s_waitcnt vmcnt(8)" ::: "memory");   // tile t+1 landed
    } else {
      asm volatile("s_waitcnt vmcnt(0)" ::: "memory");
    }
    __builtin_amdgcn_s_barrier();        // buf[(t+1)&1] ready for all
    __builtin_amdgcn_sched_barrier(0);
  }
#undef STAGE

  const float* rs = invc + (size_t)z * HW;
  float* C = simout + (size_t)z * HW * HW;
  int m0 = bx * 256, n0 = by * 256;
#pragma unroll
  for (int mf = 0; mf < 8; mf++) {
    int mb = m0 + wr * 128 + mf * 16 + l16 * 4;
#pragma unroll
    for (int r = 0; r < 4; r++) {
      float sc = rs[mb + r];
#pragma unroll
      for (int nf = 0; nf < 4; nf++) {
        int n = n0 + wc * 64 + nf * 16 + fcol;
        C[(size_t)(mb + r) * HW + n] = acc[mf][nf][r] * sc;
      }
    }
  }
}

// Partial argmax over hw chunks of 1024; first-occurrence tie-break.
__global__ __launch_bounds__(256) void argmax_part_k(const float* __restrict__ sim,
                                                     float* __restrict__ pmax,
                                                     int* __restrict__ pidx) {
  int s = blockIdx.z, hwc = blockIdx.y, xy0 = blockIdx.x * 64;
  int tid = threadIdx.x, xl = tid & 63, r = tid >> 6;
  const float* base = sim + ((size_t)s * HW + hwc * 1024) * HW + xy0 + xl;
  float bv = -FLT_MAX;
  int bi = 0x7fffffff;
  for (int t = 0; t < 256; t++) {
    int hw = r + 4 * t;
    float v = base[(size_t)hw * HW];
    if (v > bv) { bv = v; bi = hwc * 1024 + hw; }
  }
  __shared__ float sv[256];
  __shared__ int si[256];
  sv[tid] = bv;
  si[tid] = bi;
  __syncthreads();
  if (r == 0) {
    for (int rr = 1; rr < 4; rr++) {
      float v = sv[tid + 64 * rr];
      int i = si[tid + 64 * rr];
      if (v > bv || (v == bv && i < bi)) { bv = v; bi = i; }
    }
    int o = (s * 4 + hwc) * HW + xy0 + xl;
    pmax[o] = bv;
    pidx[o] = bi;
  }
}

__global__ __launch_bounds__(256) void votes_k(const float* __restrict__ pmax,
                                               const int* __restrict__ pidx,
                                               const int* __restrict__ mask,
                                               float* __restrict__ out) {
  int xy = blockIdx.x * 256 + threadIdx.x;
  int vote = 0;
  for (int s = 0; s < SREF; s++) {
    float bv = -FLT_MAX;
    int bi = 0x7fffffff;
    for (int hwc = 0; hwc < 4; hwc++) {
      int o = (s * 4 + hwc) * HW + xy;
      float v = pmax[o];
      int i = pidx[o];
      if (v > bv || (v == bv && i < bi)) { bv = v; bi = i; }
    }
    vote += (mask[s * HW + bi] != 0);
  }
  out[xy] = (float)vote;
}

extern "C" void kernel_launch(void* const* d_in, const int* in_sizes, int n_in,
                              void* d_out, int out_size, void* d_ws, size_t ws_size,
                              hipStream_t stream) {
  const float* fmaps = (const float*)d_in[0];
  const int* mask = (const int*)d_in[1];
  const float* basis = (const float*)d_in[2];
  float* out = (float*)d_out;
  float* ws = (float*)d_ws;

  unsigned* fh = (unsigned*)ws;                       // blocked hi plane
  unsigned* fl = (unsigned*)(ws + 6291456);           // blocked lo plane
  float* invn = ws + 12582912;
  float* invc = ws + 12595200;
  float* counts = ws + 12607488;
  float* protos = ws + 12607552;
  float* protod = ws + 12609600;
  float* proto = ws + 12611648;
  float* pmax = ws + 12612672;
  int* pidx = (int*)(ws + 12645440);

  float* sim = out;
  float* simfwd = out + 33554432;
  float* votes = out + 33558528;
  unsigned* Ach = (unsigned*)out;                     // blocked Acomb
  unsigned* Acl = (unsigned*)(out + 786432);
  float* coef = out + 1572864;
  float* Xd = out + 5767168;

  // 1) fn = l2norm(fmaps, C) -> blocked split planes (3 frames)
  colnorm_k<<<dim3(TFR * 64), 256, 0, stream>>>(fmaps, invn);
  scale_pack_k<<<dim3(TFR * 2048), 256, 0, stream>>>(fmaps, invn, fh, fl);

  // 2) blocked Acomb: projector + padded basis
  proj_pack_k<<<dim3(16, 16), 256, 0, stream>>>(basis, Ach, Acl);
  pack_basis_k<<<dim3(512), 256, 0, stream>>>(basis, Ach, Acl);

  // 3) batched debias: coef (z<2) + Xd (z=2)
  gemm3d_k<<<dim3(12, 32, 3), 256, 0, stream>>>(Ach, Acl, fh, fl, Xd, coef);
  normref_k<<<dim3(64, 2), 256, 0, stream>>>(coef, invc);

  // 4) tgt renorm + repack into planes frame 2
  colnorm_k<<<dim3(64), 256, 0, stream>>>(Xd, invc + 2 * HW);
  scale_pack_k<<<dim3(2048), 256, 0, stream>>>(Xd, invc + 2 * HW,
                                               fh + (size_t)2 * 2097152,
                                               fl + (size_t)2 * 2097152);

  // 5) prototype
  count_k<<<2, 256, 0, stream>>>(mask, counts);
  proto_k<<<256, 256, 0, stream>>>(fh, fl, mask, invc, protos);
  protomv_k<<<8, 256, 0, stream>>>(Ach, Acl, protos, protod);
  protonorm_k<<<1, 256, 0, stream>>>(protod, counts, proto);

  // 6) sim_fwd
  simfwd_k<<<16, 256, 0, stream>>>(fh, fl, proto, simfwd);

  // 7) sim (256² gload_lds pipeline)
  simg_k<<<dim3(16, 16, 2), 512, 0, stream>>>(fh, fl, invc, sim);

  // 8) votes
  argmax_part_k<<<dim3(64, 4, 2), 256, 0, stream>>>(sim, pmax, pidx);
  votes_k<<<16, 256, 0, stream>>>(pmax, pidx, mask, votes);
}

// Round 9
// 595.209 us; speedup vs baseline: 1.1808x; 1.0291x over previous
//
#include <hip/hip_runtime.h>
#include <hip/hip_bf16.h>
#include <cfloat>

#define CH   1024
#define HW   4096
#define NSVD 500
#define TFR  3
#define SREF 2

typedef __attribute__((ext_vector_type(4))) float f32x4;
typedef __attribute__((ext_vector_type(4))) unsigned int u32x4;
typedef __attribute__((ext_vector_type(8))) short short8;

// ---------------------------------------------------------------------------
// Split-bf16 planes in BLOCKED layout (gload_lds-friendly):
//   plane[t][cb][kgrp][cl][kp4] u32, cb = col/256, kgrp = kpair/4, cl = col%256,
//   kp4 = kpair%4. u32 (kpair r, col n) = bf16(ch 2r) | bf16(ch 2r+1)<<16.
//   Frame = 2,097,152 u32. K-tile slab (4 kgrp x 256 cl x 16B = 16 KB) contiguous.
// 3-PASS numerics everywhere (hh + h*lo(B) + lo(A)*h): proven vote-safe R2-R7.
// ws (float units): fh 0 / fl 6,291,456 / invn 12,582,912 / invc 12,595,200 /
//   counts 12,607,488 / protos 12,607,552 / protod 12,609,600 / proto 12,611,648 /
//   am 12,612,672 (2*4096 u64 = 16,384 floats; packed argmax, atomicMax)
//   end 12,629,056 < 12,678,208 (R7-proven ws envelope)
// d_out scratch (dead before simg_k writes): Ach 0, Acl 786,432,
//   coef 1,572,864 (2*512*HW f32), Xd 5,767,168 (1024*HW f32)
// ---------------------------------------------------------------------------

__device__ inline unsigned bfr(float x) {        // fp32 -> bf16 bits, RNE
  unsigned u = __float_as_uint(x);
  return (u + 0x7fffu + ((u >> 16) & 1u)) >> 16;
}
__device__ inline float lores(float x, unsigned h) {
  return x - __uint_as_float(h << 16);
}
__device__ inline float vlo(unsigned ph, unsigned pl) {
  return __uint_as_float(ph << 16) + __uint_as_float(pl << 16);
}
__device__ inline float vhi(unsigned ph, unsigned pl) {
  return __uint_as_float(ph & 0xFFFF0000u) + __uint_as_float(pl & 0xFFFF0000u);
}

// Column L2 norms over C, layout (t, c, n)
__global__ __launch_bounds__(256) void colnorm_k(const float* __restrict__ src,
                                                 float* __restrict__ inv) {
  int blk = blockIdx.x;
  int t = blk >> 6;
  int n0 = (blk & 63) * 64;
  int tid = threadIdx.x;
  int nl = tid & 63, r = tid >> 6;
  const float* base = src + (size_t)t * CH * HW + n0 + nl;
  float s = 0.f;
  for (int c = r; c < CH; c += 4) {
    float v = base[(size_t)c * HW];
    s += v * v;
  }
  __shared__ float red[256];
  red[tid] = s;
  __syncthreads();
  if (r == 0) {
    float tot = red[nl] + red[nl + 64] + red[nl + 128] + red[nl + 192];
    inv[t * HW + n0 + nl] = 1.0f / fmaxf(sqrtf(tot), 1e-12f);
  }
}

// blocked planes <- pack(src[t,c,n]*inv[t,n]); thread owns (t, kgrp, n)
__global__ __launch_bounds__(256) void scale_pack_k(const float* __restrict__ src,
                                                    const float* __restrict__ inv,
                                                    unsigned* __restrict__ Gh,
                                                    unsigned* __restrict__ Gl) {
  int gid = blockIdx.x * 256 + threadIdx.x;
  int lt = gid >> 19;
  int kg = (gid >> 12) & 127;
  int n = gid & 4095;
  const float* s0 = src + ((size_t)lt * CH + kg * 8) * HW + n;
  float w = inv[lt * HW + n];
  unsigned oh[4], ol[4];
#pragma unroll
  for (int j = 0; j < 4; j++) {
    float a = s0[(size_t)(2 * j) * HW] * w;
    float b = s0[(size_t)(2 * j + 1) * HW] * w;
    unsigned ha = bfr(a), hb = bfr(b);
    oh[j] = ha | (hb << 16);
    ol[j] = bfr(lores(a, ha)) | (bfr(lores(b, hb)) << 16);
  }
  size_t vi = (((size_t)lt * 16 + (n >> 8)) * 128 + kg) * 256 + (n & 255);
  *reinterpret_cast<u32x4*>(Gh + vi * 4) = *reinterpret_cast<u32x4*>(oh);
  *reinterpret_cast<u32x4*>(Gl + vi * 4) = *reinterpret_cast<u32x4*>(ol);
}

// Acomb cols 0..1023: P = I - basis@basis^T, blocked write
__global__ __launch_bounds__(256) void proj_pack_k(const float* __restrict__ bas,
                                                   unsigned* __restrict__ Ah,
                                                   unsigned* __restrict__ Al) {
  int m0 = blockIdx.x * 64, n0 = blockIdx.y * 64;
  int tid = threadIdx.x;
  int tx = tid & 15, ty = tid >> 4;
  int lm = tid & 63, lk = tid >> 6;
  __shared__ float As[16][64];
  __shared__ float Bs[16][64];
  float acc[4][4] = {};
  for (int k0 = 0; k0 < 512; k0 += 16) {
#pragma unroll
    for (int i = 0; i < 4; i++) {
      int k = k0 + lk * 4 + i;
      As[lk * 4 + i][lm] = (k < NSVD) ? bas[(size_t)(m0 + lm) * NSVD + k] : 0.f;
      Bs[lk * 4 + i][lm] = (k < NSVD) ? bas[(size_t)(n0 + lm) * NSVD + k] : 0.f;
    }
    __syncthreads();
#pragma unroll
    for (int kk = 0; kk < 16; kk++) {
      float a[4], b[4];
#pragma unroll
      for (int i = 0; i < 4; i++) a[i] = As[kk][ty * 4 + i];
#pragma unroll
      for (int j = 0; j < 4; j++) b[j] = Bs[kk][tx * 4 + j];
#pragma unroll
      for (int i = 0; i < 4; i++)
#pragma unroll
        for (int j = 0; j < 4; j++) acc[i][j] += a[i] * b[j];
    }
    __syncthreads();
  }
#pragma unroll
  for (int jp = 0; jp < 2; jp++) {
    int r = n0 / 2 + tx * 2 + jp;     // kpair
#pragma unroll
    for (int i = 0; i < 4; i++) {
      int c = m0 + ty * 4 + i;        // column
      float va = ((c == 2 * r) ? 1.0f : 0.0f) - acc[i][2 * jp];
      float vb = ((c == 2 * r + 1) ? 1.0f : 0.0f) - acc[i][2 * jp + 1];
      unsigned ha = bfr(va), hb = bfr(vb);
      size_t vi = ((size_t)((c >> 8) * 128 + (r >> 2)) * 256 + (c & 255)) * 4 + (r & 3);
      Ah[vi] = ha | (hb << 16);
      Al[vi] = bfr(lores(va, ha)) | (bfr(lores(vb, hb)) << 16);
    }
  }
}

// Acomb cols 1024..1535: basis zero-padded to 512 svd rows
__global__ __launch_bounds__(256) void pack_basis_k(const float* __restrict__ bas,
                                                    unsigned* __restrict__ Ah,
                                                    unsigned* __restrict__ Al) {
  int r = blockIdx.x;                 // kpair = channel pair
  for (int m = threadIdx.x; m < 512; m += 256) {
    float b0 = (m < NSVD) ? bas[(size_t)(2 * r) * NSVD + m] : 0.f;
    float b1 = (m < NSVD) ? bas[(size_t)(2 * r + 1) * NSVD + m] : 0.f;
    unsigned h0 = bfr(b0), h1 = bfr(b1);
    int c = 1024 + m;
    size_t vi = ((size_t)((c >> 8) * 128 + (r >> 2)) * 256 + (c & 255)) * 4 + (r & 3);
    Ah[vi] = h0 | (h1 << 16);
    Al[vi] = bfr(lores(b0, h0)) | (bfr(lores(b1, h1)) << 16);
  }
}

// invc[s*HW+n] = 1/sqrt(max(1 - sum coef^2, 0))
__global__ __launch_bounds__(256) void normref_k(const float* __restrict__ coef,
                                                 float* __restrict__ invc) {
  int s = blockIdx.y;
  int n0 = blockIdx.x * 64;
  int tid = threadIdx.x, nl = tid & 63, r = tid >> 6;
  const float* base = coef + (size_t)s * 512 * HW + n0 + nl;
  float s2 = 0.f;
  for (int m = r; m < 512; m += 4) {
    float v = base[(size_t)m * HW];
    s2 += v * v;
  }
  __shared__ float red[256];
  red[tid] = s2;
  __syncthreads();
  if (r == 0) {
    float tot = red[nl] + red[nl + 64] + red[nl + 128] + red[nl + 192];
    invc[s * HW + n0 + nl] = 1.0f / fmaxf(sqrtf(fmaxf(1.0f - tot, 0.0f)), 1e-12f);
  }
}

__global__ __launch_bounds__(256) void count_k(const int* __restrict__ mask,
                                               float* __restrict__ counts) {
  int s = blockIdx.x;
  int tid = threadIdx.x;
  int c = 0;
  for (int i = tid; i < HW; i += 256) c += (mask[s * HW + i] != 0);
  __shared__ int red[256];
  red[tid] = c;
  __syncthreads();
  for (int o = 128; o > 0; o >>= 1) {
    if (tid < o) red[tid] += red[tid + o];
    __syncthreads();
  }
  if (tid == 0) counts[s] = fmaxf((float)red[0], 1.0f);
}

// protos[s*CH+c] = sum_n mask*fn*invc; block = (s, kgrp of 8 channels)
__global__ __launch_bounds__(256) void proto_k(const unsigned* __restrict__ Gh,
                                               const unsigned* __restrict__ Gl,
                                               const int* __restrict__ mask,
                                               const float* __restrict__ invc,
                                               float* __restrict__ protos) {
  int s = blockIdx.x >> 7, kg = blockIdx.x & 127;
  int tid = threadIdx.x;
  const u32x4* Hv = (const u32x4*)Gh + (size_t)s * 524288;
  const u32x4* Lv = (const u32x4*)Gl + (size_t)s * 524288;
  float a[8] = {};
  for (int n = tid; n < HW; n += 256) {
    if (mask[s * HW + n]) {
      float w = invc[s * HW + n];
      size_t vi = ((size_t)(n >> 8) * 128 + kg) * 256 + (n & 255);
      u32x4 h = Hv[vi], l = Lv[vi];
#pragma unroll
      for (int j = 0; j < 4; j++) {
        a[2 * j] += vlo(h[j], l[j]) * w;
        a[2 * j + 1] += vhi(h[j], l[j]) * w;
      }
    }
  }
  __shared__ float red[256];
  for (int e = 0; e < 8; e++) {
    red[tid] = a[e];
    __syncthreads();
    for (int o = 128; o > 0; o >>= 1) {
      if (tid < o) red[tid] += red[tid + o];
      __syncthreads();
    }
    if (tid == 0) protos[s * CH + kg * 8 + e] = red[0];
    __syncthreads();
  }
}

// protod[s*CH+c] = sum_k P[c][k]*protos[s][k]  (blocked Acomb, symmetric P)
__global__ __launch_bounds__(256) void protomv_k(const unsigned* __restrict__ Ah,
                                                 const unsigned* __restrict__ Al,
                                                 const float* __restrict__ protos,
                                                 float* __restrict__ protod) {
  int s = blockIdx.x >> 2;
  int c = (blockIdx.x & 3) * 256 + threadIdx.x;
  __shared__ float w[CH];
  for (int k = threadIdx.x; k < CH; k += 256) w[k] = protos[s * CH + k];
  __syncthreads();
  float acc = 0.f;
  for (int r = 0; r < 512; r++) {
    size_t vi = ((size_t)((c >> 8) * 128 + (r >> 2)) * 256 + (c & 255)) * 4 + (r & 3);
    unsigned h = Ah[vi], l = Al[vi];
    acc += vlo(h, l) * w[2 * r] + vhi(h, l) * w[2 * r + 1];
  }
  protod[s * CH + c] = acc;
}

__global__ __launch_bounds__(256) void protonorm_k(const float* __restrict__ protod,
                                                   const float* __restrict__ counts,
                                                   float* __restrict__ proto) {
  int tid = threadIdx.x;
  __shared__ float sm[CH];
  __shared__ float red[256];
  float c0 = counts[0], c1 = counts[1];
  float ss = 0.f;
  for (int c = tid; c < CH; c += 256) {
    float m = 0.5f * (protod[c] / c0 + protod[CH + c] / c1);
    sm[c] = m;
    ss += m * m;
  }
  red[tid] = ss;
  __syncthreads();
  for (int o = 128; o > 0; o >>= 1) {
    if (tid < o) red[tid] += red[tid + o];
    __syncthreads();
  }
  __syncthreads();
  float inv = 1.0f / fmaxf(sqrtf(red[0]), 1e-12f);
  for (int c = tid; c < CH; c += 256) proto[c] = sm[c] * inv;
}

__global__ __launch_bounds__(256) void simfwd_k(const unsigned* __restrict__ Gh,
                                                const unsigned* __restrict__ Gl,
                                                const float* __restrict__ proto,
                                                float* __restrict__ out) {
  __shared__ float p[CH];
  int tid = threadIdx.x;
  for (int c = tid; c < CH; c += 256) p[c] = proto[c];
  __syncthreads();
  int n = blockIdx.x * 256 + tid;
  const u32x4* Hv = (const u32x4*)Gh + (size_t)2 * 524288;
  const u32x4* Lv = (const u32x4*)Gl + (size_t)2 * 524288;
  float acc = 0.f;
  for (int kg = 0; kg < 128; kg++) {
    size_t vi = ((size_t)(n >> 8) * 128 + kg) * 256 + (n & 255);
    u32x4 h = Hv[vi], l = Lv[vi];
#pragma unroll
    for (int j = 0; j < 4; j++)
      acc += vlo(h[j], l[j]) * p[8 * kg + 2 * j] + vhi(h[j], l[j]) * p[8 * kg + 2 * j + 1];
  }
  out[n] = acc;
}

// ---------------------------------------------------------------------------
// Debias GEMM (2-phase 128² kernel, blocked loads, full 3-pass).
// ---------------------------------------------------------------------------
#define BM 128
#define BK 32

__device__ __forceinline__ short8 ldfrag(const unsigned* S, int loc, int q) {
  return *reinterpret_cast<const short8*>(&S[loc * 32 + ((q ^ (loc & 7)) << 2)]);
}

__global__ __launch_bounds__(256) void gemm3d_k(
    const unsigned* __restrict__ Ach, const unsigned* __restrict__ Acl,
    const unsigned* __restrict__ fh, const unsigned* __restrict__ fl,
    float* __restrict__ Xd, float* __restrict__ coef) {
  int bx = blockIdx.x, bz = blockIdx.z;
  float* Cout;
  int m0 = bx * BM, cm0 = m0;
  if (bz == 2) {
    if (bx >= 8) return;
    Cout = Xd;
  } else {
    if (bx < 8) return;
    Cout = coef + (size_t)bz * 512 * HW;
    cm0 = (bx - 8) * BM;
  }
  int n0 = blockIdx.y * BM;
  const u32x4* Ahv = (const u32x4*)Ach;
  const u32x4* Alv = (const u32x4*)Acl;
  const u32x4* Bhv = (const u32x4*)fh + (size_t)bz * 524288;
  const u32x4* Blv = (const u32x4*)fl + (size_t)bz * 524288;

  __shared__ u32x4 AsV[BM * 8];
  __shared__ u32x4 BsV[BM * 8];
  unsigned* As = (unsigned*)AsV;
  unsigned* Bs = (unsigned*)BsV;

  int tid = threadIdx.x;
  int lane = tid & 63, wave = tid >> 6;
  int wr = wave >> 1, wc = wave & 1;
  int sn = tid & 127, kq = tid >> 7;
  int fcol = lane & 15, l16 = lane >> 4;

  int colA = m0 + sn, colB = n0 + sn;
  size_t ia = (size_t)(colA >> 8) * 32768 + (colA & 255);
  size_t ib = (size_t)(colB >> 8) * 32768 + (colB & 255);

  f32x4 acc[4][4] = {};
  unsigned rah[8], ral[8], rbh[8], rbl[8];

#define LOADT(KT)                                                          \
  {                                                                        \
    int g0 = (KT) * 4 + kq * 2;                                            \
    *reinterpret_cast<u32x4*>(&rah[0]) = Ahv[ia + (size_t)g0 * 256];       \
    *reinterpret_cast<u32x4*>(&rah[4]) = Ahv[ia + (size_t)(g0 + 1) * 256]; \
    *reinterpret_cast<u32x4*>(&ral[0]) = Alv[ia + (size_t)g0 * 256];       \
    *reinterpret_cast<u32x4*>(&ral[4]) = Alv[ia + (size_t)(g0 + 1) * 256]; \
    *reinterpret_cast<u32x4*>(&rbh[0]) = Bhv[ib + (size_t)g0 * 256];       \
    *reinterpret_cast<u32x4*>(&rbh[4]) = Bhv[ib + (size_t)(g0 + 1) * 256]; \
    *reinterpret_cast<u32x4*>(&rbl[0]) = Blv[ib + (size_t)g0 * 256];       \
    *reinterpret_cast<u32x4*>(&rbl[4]) = Blv[ib + (size_t)(g0 + 1) * 256]; \
  }

  LOADT(0);

  for (int kt = 0; kt < CH / BK; ++kt) {
    __syncthreads();
    {
      int xa = sn & 7;
      int q0 = ((2 * kq) ^ xa) << 2, q1 = ((2 * kq + 1) ^ xa) << 2;
      int q2 = ((4 + 2 * kq) ^ xa) << 2, q3 = ((5 + 2 * kq) ^ xa) << 2;
      *reinterpret_cast<u32x4*>(&As[sn * 32 + q0]) = *reinterpret_cast<u32x4*>(&rah[0]);
      *reinterpret_cast<u32x4*>(&As[sn * 32 + q1]) = *reinterpret_cast<u32x4*>(&rah[4]);
      *reinterpret_cast<u32x4*>(&As[sn * 32 + q2]) = *reinterpret_cast<u32x4*>(&ral[0]);
      *reinterpret_cast<u32x4*>(&As[sn * 32 + q3]) = *reinterpret_cast<u32x4*>(&ral[4]);
      *reinterpret_cast<u32x4*>(&Bs[sn * 32 + q0]) = *reinterpret_cast<u32x4*>(&rbh[0]);
      *reinterpret_cast<u32x4*>(&Bs[sn * 32 + q1]) = *reinterpret_cast<u32x4*>(&rbh[4]);
      *reinterpret_cast<u32x4*>(&Bs[sn * 32 + q2]) = *reinterpret_cast<u32x4*>(&rbl[0]);
      *reinterpret_cast<u32x4*>(&Bs[sn * 32 + q3]) = *reinterpret_cast<u32x4*>(&rbl[4]);
    }
    __syncthreads();

    if (kt + 1 < CH / BK) LOADT(kt + 1);

    short8 bhf[4], blf[4];
#pragma unroll
    for (int nf = 0; nf < 4; nf++) {
      int nloc = wc * 64 + nf * 16 + fcol;
      bhf[nf] = ldfrag(Bs, nloc, l16);
      blf[nf] = ldfrag(Bs, nloc, 4 + l16);
    }
#pragma unroll
    for (int mf = 0; mf < 4; mf++) {
      int mloc = wr * 64 + mf * 16 + fcol;
      short8 ah = ldfrag(As, mloc, l16);
      short8 al = ldfrag(As, mloc, 4 + l16);
#pragma unroll
      for (int nf = 0; nf < 4; nf++) {
        acc[mf][nf] = __builtin_amdgcn_mfma_f32_16x16x32_bf16(ah, bhf[nf], acc[mf][nf], 0, 0, 0);
        acc[mf][nf] = __builtin_amdgcn_mfma_f32_16x16x32_bf16(ah, blf[nf], acc[mf][nf], 0, 0, 0);
        acc[mf][nf] = __builtin_amdgcn_mfma_f32_16x16x32_bf16(al, bhf[nf], acc[mf][nf], 0, 0, 0);
      }
    }
  }
#undef LOADT

  int rbase = l16 * 4;
#pragma unroll
  for (int mf = 0; mf < 4; mf++) {
    int mbase = cm0 + wr * 64 + mf * 16 + rbase;
#pragma unroll
    for (int r = 0; r < 4; r++) {
#pragma unroll
      for (int nf = 0; nf < 4; nf++) {
        int n = n0 + wc * 64 + nf * 16 + fcol;
        Cout[(size_t)(mbase + r) * HW + n] = acc[mf][nf][r];
      }
    }
  }
}

// ---------------------------------------------------------------------------
// sim GEMM: 256x256 tile, 8 waves, full 3-pass (4 slabs), depth-2 gload_lds
// pipeline (2 x 64 KB LDS), counted vmcnt, fused argmax via packed atomicMax.
// ---------------------------------------------------------------------------
#define SIMG_NT 32

__global__ __launch_bounds__(512, 2) void simg_k(
    const unsigned* __restrict__ Gh, const unsigned* __restrict__ Gl,
    const float* __restrict__ invc, float* __restrict__ simout,
    unsigned long long* __restrict__ amg) {
  __shared__ __align__(16) unsigned smem[32768];   // 128 KB, 2 x 64 KB bufs

  int orig = (blockIdx.z * 16 + blockIdx.y) * 16 + blockIdx.x;
  int lin = (orig & 7) * 64 + (orig >> 3);         // XCD-contiguous, bijective
  int z = lin >> 8, bx = (lin >> 4) & 15, by = lin & 15;

  const unsigned* srcs[4];
  srcs[0] = Gh + (size_t)z * 2097152 + (size_t)bx * 131072;   // Ah
  srcs[1] = Gl + (size_t)z * 2097152 + (size_t)bx * 131072;   // Al
  srcs[2] = Gh + (size_t)2 * 2097152 + (size_t)by * 131072;   // Bh
  srcs[3] = Gl + (size_t)2 * 2097152 + (size_t)by * 131072;   // Bl

  int tid = threadIdx.x, ln = tid & 63, wv = tid >> 6;
  int wr = wv >> 2, wc = wv & 3;
  int fcol = ln & 15, l16 = ln >> 4;

  f32x4 acc[8][4] = {};

#define STAGE(BSEL, T)                                                        \
  {                                                                           \
    _Pragma("unroll")                                                         \
    for (int op = 0; op < 4; op++) {                                          \
      const unsigned* gs = srcs[op] + (size_t)(T) * 4096;                     \
      _Pragma("unroll")                                                       \
      for (int rr = 0; rr < 2; rr++) {                                        \
        int slot = rr * 512 + wv * 64;                                        \
        __builtin_amdgcn_global_load_lds(                                     \
            (const __attribute__((address_space(1))) unsigned*)(gs + (size_t)(slot + ln) * 4), \
            (__attribute__((address_space(3))) unsigned*)(smem + (BSEL) * 16384 + op * 4096 + slot * 4), \
            16, 0, 0);                                                        \
      }                                                                       \
    }                                                                         \
  }

  STAGE(0, 0);
  STAGE(1, 1);
  asm volatile("s_waitcnt vmcnt(8)" ::: "memory");
  __builtin_amdgcn_s_barrier();
  __builtin_amdgcn_sched_barrier(0);

  for (int t = 0; t < SIMG_NT; ++t) {
    const unsigned* Sb = smem + (t & 1) * 16384;
    short8 bh[4], bl[4];
#pragma unroll
    for (int nf = 0; nf < 4; nf++) {
      int nloc = wc * 64 + nf * 16 + fcol;
      bh[nf] = *reinterpret_cast<const short8*>(Sb + 2 * 4096 + l16 * 1024 + nloc * 4);
      bl[nf] = *reinterpret_cast<const short8*>(Sb + 3 * 4096 + l16 * 1024 + nloc * 4);
    }
    __builtin_amdgcn_s_setprio(1);
#pragma unroll
    for (int mf = 0; mf < 8; mf++) {
      int mloc = wr * 128 + mf * 16 + fcol;
      short8 ah = *reinterpret_cast<const short8*>(Sb + l16 * 1024 + mloc * 4);
      short8 al = *reinterpret_cast<const short8*>(Sb + 4096 + l16 * 1024 + mloc * 4);
#pragma unroll
      for (int nf = 0; nf < 4; nf++) {
        acc[mf][nf] = __builtin_amdgcn_mfma_f32_16x16x32_bf16(ah, bh[nf], acc[mf][nf], 0, 0, 0);
        acc[mf][nf] = __builtin_amdgcn_mfma_f32_16x16x32_bf16(ah, bl[nf], acc[mf][nf], 0, 0, 0);
        acc[mf][nf] = __builtin_amdgcn_mfma_f32_16x16x32_bf16(al, bh[nf], acc[mf][nf], 0, 0, 0);
      }
    }
    __builtin_amdgcn_s_setprio(0);
    asm volatile("s_waitcnt lgkmcnt(0)" ::: "memory");
    __builtin_amdgcn_s_barrier();        // all waves done reading buf[t&1]
    __builtin_amdgcn_sched_barrier(0);
    if (t + 2 < SIMG_NT) {
      STAGE(t & 1, t + 2);
      asm volatile("s_waitcnt vmcnt(8)" ::: "memory");   // tile t+1 landed
    } else {
      asm volatile("s_waitcnt vmcnt(0)" ::: "memory");
    }
    __builtin_amdgcn_s_barrier();        // buf[(t+1)&1] ready for all
    __builtin_amdgcn_sched_barrier(0);
  }
#undef STAGE

  // epilogue: row-scaled C write + fused column-argmax via packed atomicMax
  const float* rs = invc + (size_t)z * HW;
  float* C = simout + (size_t)z * HW * HW;
  unsigned long long* am = amg + (size_t)z * HW;
  int m0 = bx * 256, n0 = by * 256;
  int ncol[4];
#pragma unroll
  for (int nf = 0; nf < 4; nf++) ncol[nf] = n0 + wc * 64 + nf * 16 + fcol;
  float bv[4] = {-FLT_MAX, -FLT_MAX, -FLT_MAX, -FLT_MAX};
  int bi[4] = {0, 0, 0, 0};
#pragma unroll
  for (int mf = 0; mf < 8; mf++) {
    int mg = m0 + wr * 128 + mf * 16 + l16 * 4;
#pragma unroll
    for (int r = 0; r < 4; r++) {
      float sc = rs[mg + r];
#pragma unroll
      for (int nf = 0; nf < 4; nf++) {
        float val = acc[mf][nf][r] * sc;
        C[(size_t)(mg + r) * HW + ncol[nf]] = val;
        if (val > bv[nf]) { bv[nf] = val; bi[nf] = mg + r; }   // ascending m
      }
    }
  }
#pragma unroll
  for (int nf = 0; nf < 4; nf++) {
#pragma unroll
    for (int st = 16; st <= 32; st <<= 1) {
      float ov = __shfl_xor(bv[nf], st, 64);
      int oi = __shfl_xor(bi[nf], st, 64);
      if (ov > bv[nf] || (ov == bv[nf] && oi < bi[nf])) { bv[nf] = ov; bi[nf] = oi; }
    }
  }
  if (ln < 16) {
#pragma unroll
    for (int nf = 0; nf < 4; nf++) {
      unsigned b = __float_as_uint(bv[nf]);
      unsigned key = (b & 0x80000000u) ? ~b : (b | 0x80000000u);
      unsigned long long packed =
          ((unsigned long long)key << 32) | (unsigned)(~bi[nf]);
      atomicMax(am + ncol[nf], packed);
    }
  }
}

__global__ __launch_bounds__(256) void votes_k(const unsigned long long* __restrict__ am,
                                               const int* __restrict__ mask,
                                               float* __restrict__ out) {
  int xy = blockIdx.x * 256 + threadIdx.x;
  int vote = 0;
  for (int s = 0; s < SREF; s++) {
    unsigned long long p = am[(size_t)s * HW + xy];
    int bi = (int)(~(unsigned)p);
    vote += (mask[s * HW + bi] != 0);
  }
  out[xy] = (float)vote;
}

extern "C" void kernel_launch(void* const* d_in, const int* in_sizes, int n_in,
                              void* d_out, int out_size, void* d_ws, size_t ws_size,
                              hipStream_t stream) {
  const float* fmaps = (const float*)d_in[0];
  const int* mask = (const int*)d_in[1];
  const float* basis = (const float*)d_in[2];
  float* out = (float*)d_out;
  float* ws = (float*)d_ws;

  unsigned* fh = (unsigned*)ws;                       // blocked hi plane
  unsigned* fl = (unsigned*)(ws + 6291456);           // blocked lo plane
  float* invn = ws + 12582912;
  float* invc = ws + 12595200;
  float* counts = ws + 12607488;
  float* protos = ws + 12607552;
  float* protod = ws + 12609600;
  float* proto = ws + 12611648;
  unsigned long long* am = (unsigned long long*)(ws + 12612672);   // 2*HW u64

  float* sim = out;
  float* simfwd = out + 33554432;
  float* votes = out + 33558528;
  unsigned* Ach = (unsigned*)out;                     // blocked Acomb (hi)
  unsigned* Acl = (unsigned*)(out + 786432);          // blocked Acomb (lo)
  float* coef = out + 1572864;
  float* Xd = out + 5767168;

  // 0) zero the packed-argmax array (graph-capture-safe)
  hipMemsetAsync(am, 0, (size_t)SREF * HW * sizeof(unsigned long long), stream);

  // 1) fn = l2norm(fmaps, C) -> blocked split planes (3 frames)
  colnorm_k<<<dim3(TFR * 64), 256, 0, stream>>>(fmaps, invn);
  scale_pack_k<<<dim3(TFR * 2048), 256, 0, stream>>>(fmaps, invn, fh, fl);

  // 2) blocked Acomb: projector + padded basis
  proj_pack_k<<<dim3(16, 16), 256, 0, stream>>>(basis, Ach, Acl);
  pack_basis_k<<<dim3(512), 256, 0, stream>>>(basis, Ach, Acl);

  // 3) batched debias: coef (z<2) + Xd (z=2), full 3-pass
  gemm3d_k<<<dim3(12, 32, 3), 256, 0, stream>>>(Ach, Acl, fh, fl, Xd, coef);
  normref_k<<<dim3(64, 2), 256, 0, stream>>>(coef, invc);

  // 4) tgt renorm + repack into planes frame 2
  colnorm_k<<<dim3(64), 256, 0, stream>>>(Xd, invc + 2 * HW);
  scale_pack_k<<<dim3(2048), 256, 0, stream>>>(Xd, invc + 2 * HW,
                                               fh + (size_t)2 * 2097152,
                                               fl + (size_t)2 * 2097152);

  // 5) prototype
  count_k<<<2, 256, 0, stream>>>(mask, counts);
  proto_k<<<256, 256, 0, stream>>>(fh, fl, mask, invc, protos);
  protomv_k<<<8, 256, 0, stream>>>(Ach, Acl, protos, protod);
  protonorm_k<<<1, 256, 0, stream>>>(protod, counts, proto);

  // 6) sim_fwd
  simfwd_k<<<16, 256, 0, stream>>>(fh, fl, proto, simfwd);

  // 7) sim (256², 3-pass, depth-2 pipeline, fused atomic argmax)
  simg_k<<<dim3(16, 16, 2), 512, 0, stream>>>(fh, fl, invc, sim, am);

  // 8) votes (read final argmax directly)
  votes_k<<<16, 256, 0, stream>>>(am, mask, votes);
}

// Round 10
// 530.143 us; speedup vs baseline: 1.3257x; 1.1227x over previous
//
#include <hip/hip_runtime.h>
#include <hip/hip_bf16.h>
#include <cfloat>

#define CH   1024
#define HW   4096
#define NSVD 500
#define TFR  3
#define SREF 2

typedef __attribute__((ext_vector_type(4))) float f32x4;
typedef __attribute__((ext_vector_type(4))) unsigned int u32x4;
typedef __attribute__((ext_vector_type(8))) short short8;

// ---------------------------------------------------------------------------
// Split-bf16 planes in BLOCKED layout (gload_lds-friendly):
//   plane[t][cb][kgrp][cl][kp4] u32. K-tile slab (16 KB) contiguous.
// 3-PASS numerics (hh + h*lo(B) + lo(A)*h): proven vote-safe.
// simg phase-split: 3 phases/K-tile (one per pass), slab-granular staging,
//   counted vmcnt {10,10,12} -> pipeline never drains. Bit-identical to R9.
// ws (float units): fh 0 / fl 6,291,456 / invn 12,582,912 / invc 12,595,200 /
//   protos 12,607,552 / proto 12,611,648 / am 12,612,672 (2*4096 u64) /
//   part 12,629,056 (8*2048) -> end 12,645,440 (proven envelope)
// d_out scratch: Ach 0, Acl 786,432, coef 1,572,864, Xd 5,767,168
// ---------------------------------------------------------------------------

__device__ inline unsigned bfr(float x) {        // fp32 -> bf16 bits, RNE
  unsigned u = __float_as_uint(x);
  return (u + 0x7fffu + ((u >> 16) & 1u)) >> 16;
}
__device__ inline float lores(float x, unsigned h) {
  return x - __uint_as_float(h << 16);
}
__device__ inline float vlo(unsigned ph, unsigned pl) {
  return __uint_as_float(ph << 16) + __uint_as_float(pl << 16);
}
__device__ inline float vhi(unsigned ph, unsigned pl) {
  return __uint_as_float(ph & 0xFFFF0000u) + __uint_as_float(pl & 0xFFFF0000u);
}

// Column L2 norms over C, layout (t, c, n)
__global__ __launch_bounds__(256) void colnorm_k(const float* __restrict__ src,
                                                 float* __restrict__ inv) {
  int blk = blockIdx.x;
  int t = blk >> 6;
  int n0 = (blk & 63) * 64;
  int tid = threadIdx.x;
  int nl = tid & 63, r = tid >> 6;
  const float* base = src + (size_t)t * CH * HW + n0 + nl;
  float s = 0.f;
  for (int c = r; c < CH; c += 4) {
    float v = base[(size_t)c * HW];
    s += v * v;
  }
  __shared__ float red[256];
  red[tid] = s;
  __syncthreads();
  if (r == 0) {
    float tot = red[nl] + red[nl + 64] + red[nl + 128] + red[nl + 192];
    inv[t * HW + n0 + nl] = 1.0f / fmaxf(sqrtf(tot), 1e-12f);
  }
}

// blocked planes <- pack(src[t,c,n]*inv[t,n]); thread owns (t, kgrp, n)
__global__ __launch_bounds__(256) void scale_pack_k(const float* __restrict__ src,
                                                    const float* __restrict__ inv,
                                                    unsigned* __restrict__ Gh,
                                                    unsigned* __restrict__ Gl) {
  int gid = blockIdx.x * 256 + threadIdx.x;
  int lt = gid >> 19;
  int kg = (gid >> 12) & 127;
  int n = gid & 4095;
  const float* s0 = src + ((size_t)lt * CH + kg * 8) * HW + n;
  float w = inv[lt * HW + n];
  unsigned oh[4], ol[4];
#pragma unroll
  for (int j = 0; j < 4; j++) {
    float a = s0[(size_t)(2 * j) * HW] * w;
    float b = s0[(size_t)(2 * j + 1) * HW] * w;
    unsigned ha = bfr(a), hb = bfr(b);
    oh[j] = ha | (hb << 16);
    ol[j] = bfr(lores(a, ha)) | (bfr(lores(b, hb)) << 16);
  }
  size_t vi = (((size_t)lt * 16 + (n >> 8)) * 128 + kg) * 256 + (n & 255);
  *reinterpret_cast<u32x4*>(Gh + vi * 4) = *reinterpret_cast<u32x4*>(oh);
  *reinterpret_cast<u32x4*>(Gl + vi * 4) = *reinterpret_cast<u32x4*>(ol);
}

// Acomb cols 0..1023: P = I - basis@basis^T, blocked write
__global__ __launch_bounds__(256) void proj_pack_k(const float* __restrict__ bas,
                                                   unsigned* __restrict__ Ah,
                                                   unsigned* __restrict__ Al) {
  int m0 = blockIdx.x * 64, n0 = blockIdx.y * 64;
  int tid = threadIdx.x;
  int tx = tid & 15, ty = tid >> 4;
  int lm = tid & 63, lk = tid >> 6;
  __shared__ float As[16][64];
  __shared__ float Bs[16][64];
  float acc[4][4] = {};
  for (int k0 = 0; k0 < 512; k0 += 16) {
#pragma unroll
    for (int i = 0; i < 4; i++) {
      int k = k0 + lk * 4 + i;
      As[lk * 4 + i][lm] = (k < NSVD) ? bas[(size_t)(m0 + lm) * NSVD + k] : 0.f;
      Bs[lk * 4 + i][lm] = (k < NSVD) ? bas[(size_t)(n0 + lm) * NSVD + k] : 0.f;
    }
    __syncthreads();
#pragma unroll
    for (int kk = 0; kk < 16; kk++) {
      float a[4], b[4];
#pragma unroll
      for (int i = 0; i < 4; i++) a[i] = As[kk][ty * 4 + i];
#pragma unroll
      for (int j = 0; j < 4; j++) b[j] = Bs[kk][tx * 4 + j];
#pragma unroll
      for (int i = 0; i < 4; i++)
#pragma unroll
        for (int j = 0; j < 4; j++) acc[i][j] += a[i] * b[j];
    }
    __syncthreads();
  }
#pragma unroll
  for (int jp = 0; jp < 2; jp++) {
    int r = n0 / 2 + tx * 2 + jp;     // kpair
#pragma unroll
    for (int i = 0; i < 4; i++) {
      int c = m0 + ty * 4 + i;        // column
      float va = ((c == 2 * r) ? 1.0f : 0.0f) - acc[i][2 * jp];
      float vb = ((c == 2 * r + 1) ? 1.0f : 0.0f) - acc[i][2 * jp + 1];
      unsigned ha = bfr(va), hb = bfr(vb);
      size_t vi = ((size_t)((c >> 8) * 128 + (r >> 2)) * 256 + (c & 255)) * 4 + (r & 3);
      Ah[vi] = ha | (hb << 16);
      Al[vi] = bfr(lores(va, ha)) | (bfr(lores(vb, hb)) << 16);
    }
  }
}

// Acomb cols 1024..1535: basis zero-padded to 512 svd rows
__global__ __launch_bounds__(256) void pack_basis_k(const float* __restrict__ bas,
                                                    unsigned* __restrict__ Ah,
                                                    unsigned* __restrict__ Al) {
  int r = blockIdx.x;                 // kpair = channel pair
  for (int m = threadIdx.x; m < 512; m += 256) {
    float b0 = (m < NSVD) ? bas[(size_t)(2 * r) * NSVD + m] : 0.f;
    float b1 = (m < NSVD) ? bas[(size_t)(2 * r + 1) * NSVD + m] : 0.f;
    unsigned h0 = bfr(b0), h1 = bfr(b1);
    int c = 1024 + m;
    size_t vi = ((size_t)((c >> 8) * 128 + (r >> 2)) * 256 + (c & 255)) * 4 + (r & 3);
    Ah[vi] = h0 | (h1 << 16);
    Al[vi] = bfr(lores(b0, h0)) | (bfr(lores(b1, h1)) << 16);
  }
}

// invc[s*HW+n] = 1/sqrt(max(1 - sum coef^2, 0))
__global__ __launch_bounds__(256) void normref_k(const float* __restrict__ coef,
                                                 float* __restrict__ invc) {
  int s = blockIdx.y;
  int n0 = blockIdx.x * 64;
  int tid = threadIdx.x, nl = tid & 63, r = tid >> 6;
  const float* base = coef + (size_t)s * 512 * HW + n0 + nl;
  float s2 = 0.f;
  for (int m = r; m < 512; m += 4) {
    float v = base[(size_t)m * HW];
    s2 += v * v;
  }
  __shared__ float red[256];
  red[tid] = s2;
  __syncthreads();
  if (r == 0) {
    float tot = red[nl] + red[nl + 64] + red[nl + 128] + red[nl + 192];
    invc[s * HW + n0 + nl] = 1.0f / fmaxf(sqrtf(fmaxf(1.0f - tot, 0.0f)), 1e-12f);
  }
}

// protos[s*CH+c] = sum_n mask*fn*invc; block = (s, kgrp of 8 channels)
__global__ __launch_bounds__(256) void proto_k(const unsigned* __restrict__ Gh,
                                               const unsigned* __restrict__ Gl,
                                               const int* __restrict__ mask,
                                               const float* __restrict__ invc,
                                               float* __restrict__ protos) {
  int s = blockIdx.x >> 7, kg = blockIdx.x & 127;
  int tid = threadIdx.x;
  const u32x4* Hv = (const u32x4*)Gh + (size_t)s * 524288;
  const u32x4* Lv = (const u32x4*)Gl + (size_t)s * 524288;
  float a[8] = {};
  for (int n = tid; n < HW; n += 256) {
    if (mask[s * HW + n]) {
      float w = invc[s * HW + n];
      size_t vi = ((size_t)(n >> 8) * 128 + kg) * 256 + (n & 255);
      u32x4 h = Hv[vi], l = Lv[vi];
#pragma unroll
      for (int j = 0; j < 4; j++) {
        a[2 * j] += vlo(h[j], l[j]) * w;
        a[2 * j + 1] += vhi(h[j], l[j]) * w;
      }
    }
  }
  __shared__ float red[256];
  for (int e = 0; e < 8; e++) {
    red[tid] = a[e];
    __syncthreads();
    for (int o = 128; o > 0; o >>= 1) {
      if (tid < o) red[tid] += red[tid + o];
      __syncthreads();
    }
    if (tid == 0) protos[s * CH + kg * 8 + e] = red[0];
    __syncthreads();
  }
}

// part[kc][s*CH+c] = sum_{r in kc-chunk} P[c][k]*protos[s][k]; grid (8, 8)
__global__ __launch_bounds__(256) void protomv_k(const unsigned* __restrict__ Ah,
                                                 const unsigned* __restrict__ Al,
                                                 const float* __restrict__ protos,
                                                 float* __restrict__ part) {
  int s = blockIdx.x >> 2;
  int c = (blockIdx.x & 3) * 256 + threadIdx.x;
  int kc = blockIdx.y;
  __shared__ float w[128];
  if (threadIdx.x < 128) w[threadIdx.x] = protos[s * CH + kc * 128 + threadIdx.x];
  __syncthreads();
  float acc = 0.f;
  for (int rl = 0; rl < 64; rl++) {
    int r = kc * 64 + rl;
    size_t vi = ((size_t)((c >> 8) * 128 + (r >> 2)) * 256 + (c & 255)) * 4 + (r & 3);
    unsigned h = Ah[vi], l = Al[vi];
    acc += vlo(h, l) * w[2 * rl] + vhi(h, l) * w[2 * rl + 1];
  }
  part[kc * 2048 + s * CH + c] = acc;
}

// counts + partial-sum reduce + mean + l2norm (1 block)
__global__ __launch_bounds__(256) void protonorm_k(const float* __restrict__ part,
                                                   const int* __restrict__ mask,
                                                   float* __restrict__ proto) {
  int tid = threadIdx.x;
  __shared__ float sm[CH];
  __shared__ float red[256];
  __shared__ float red2[256];
  int c0i = 0, c1i = 0;
  for (int i = tid; i < HW; i += 256) {
    c0i += (mask[i] != 0);
    c1i += (mask[HW + i] != 0);
  }
  red[tid] = (float)c0i;
  red2[tid] = (float)c1i;
  __syncthreads();
  for (int o = 128; o > 0; o >>= 1) {
    if (tid < o) { red[tid] += red[tid + o]; red2[tid] += red2[tid + o]; }
    __syncthreads();
  }
  float c0 = fmaxf(red[0], 1.0f), c1 = fmaxf(red2[0], 1.0f);
  __syncthreads();
  float ss = 0.f;
  for (int c = tid; c < CH; c += 256) {
    float p0 = 0.f, p1 = 0.f;
#pragma unroll
    for (int kc = 0; kc < 8; kc++) {
      p0 += part[kc * 2048 + c];
      p1 += part[kc * 2048 + CH + c];
    }
    float m = 0.5f * (p0 / c0 + p1 / c1);
    sm[c] = m;
    ss += m * m;
  }
  red[tid] = ss;
  __syncthreads();
  for (int o = 128; o > 0; o >>= 1) {
    if (tid < o) red[tid] += red[tid + o];
    __syncthreads();
  }
  __syncthreads();
  float inv = 1.0f / fmaxf(sqrtf(red[0]), 1e-12f);
  for (int c = tid; c < CH; c += 256) proto[c] = sm[c] * inv;
}

// sim_fwd: 64 blocks, 4-way kg split
__global__ __launch_bounds__(256) void simfwd_k(const unsigned* __restrict__ Gh,
                                                const unsigned* __restrict__ Gl,
                                                const float* __restrict__ proto,
                                                float* __restrict__ out) {
  __shared__ float p[CH];
  __shared__ float red[256];
  int tid = threadIdx.x;
  for (int c = tid; c < CH; c += 256) p[c] = proto[c];
  __syncthreads();
  int nl = tid & 63, q = tid >> 6;
  int n = blockIdx.x * 64 + nl;
  const u32x4* Hv = (const u32x4*)Gh + (size_t)2 * 524288;
  const u32x4* Lv = (const u32x4*)Gl + (size_t)2 * 524288;
  float acc = 0.f;
  for (int kg = q * 32; kg < q * 32 + 32; kg++) {
    size_t vi = ((size_t)(n >> 8) * 128 + kg) * 256 + (n & 255);
    u32x4 h = Hv[vi], l = Lv[vi];
#pragma unroll
    for (int j = 0; j < 4; j++)
      acc += vlo(h[j], l[j]) * p[8 * kg + 2 * j] + vhi(h[j], l[j]) * p[8 * kg + 2 * j + 1];
  }
  red[tid] = acc;
  __syncthreads();
  if (q == 0) out[n] = red[nl] + red[nl + 64] + red[nl + 128] + red[nl + 192];
}

// ---------------------------------------------------------------------------
// Debias GEMM (2-phase 128² kernel, blocked loads, full 3-pass).
// ---------------------------------------------------------------------------
#define BM 128
#define BK 32

__device__ __forceinline__ short8 ldfrag(const unsigned* S, int loc, int q) {
  return *reinterpret_cast<const short8*>(&S[loc * 32 + ((q ^ (loc & 7)) << 2)]);
}

__global__ __launch_bounds__(256) void gemm3d_k(
    const unsigned* __restrict__ Ach, const unsigned* __restrict__ Acl,
    const unsigned* __restrict__ fh, const unsigned* __restrict__ fl,
    float* __restrict__ Xd, float* __restrict__ coef) {
  int bx = blockIdx.x, bz = blockIdx.z;
  float* Cout;
  int m0 = bx * BM, cm0 = m0;
  if (bz == 2) {
    if (bx >= 8) return;
    Cout = Xd;
  } else {
    if (bx < 8) return;
    Cout = coef + (size_t)bz * 512 * HW;
    cm0 = (bx - 8) * BM;
  }
  int n0 = blockIdx.y * BM;
  const u32x4* Ahv = (const u32x4*)Ach;
  const u32x4* Alv = (const u32x4*)Acl;
  const u32x4* Bhv = (const u32x4*)fh + (size_t)bz * 524288;
  const u32x4* Blv = (const u32x4*)fl + (size_t)bz * 524288;

  __shared__ u32x4 AsV[BM * 8];
  __shared__ u32x4 BsV[BM * 8];
  unsigned* As = (unsigned*)AsV;
  unsigned* Bs = (unsigned*)BsV;

  int tid = threadIdx.x;
  int lane = tid & 63, wave = tid >> 6;
  int wr = wave >> 1, wc = wave & 1;
  int sn = tid & 127, kq = tid >> 7;
  int fcol = lane & 15, l16 = lane >> 4;

  int colA = m0 + sn, colB = n0 + sn;
  size_t ia = (size_t)(colA >> 8) * 32768 + (colA & 255);
  size_t ib = (size_t)(colB >> 8) * 32768 + (colB & 255);

  f32x4 acc[4][4] = {};
  unsigned rah[8], ral[8], rbh[8], rbl[8];

#define LOADT(KT)                                                          \
  {                                                                        \
    int g0 = (KT) * 4 + kq * 2;                                            \
    *reinterpret_cast<u32x4*>(&rah[0]) = Ahv[ia + (size_t)g0 * 256];       \
    *reinterpret_cast<u32x4*>(&rah[4]) = Ahv[ia + (size_t)(g0 + 1) * 256]; \
    *reinterpret_cast<u32x4*>(&ral[0]) = Alv[ia + (size_t)g0 * 256];       \
    *reinterpret_cast<u32x4*>(&ral[4]) = Alv[ia + (size_t)(g0 + 1) * 256]; \
    *reinterpret_cast<u32x4*>(&rbh[0]) = Bhv[ib + (size_t)g0 * 256];       \
    *reinterpret_cast<u32x4*>(&rbh[4]) = Bhv[ib + (size_t)(g0 + 1) * 256]; \
    *reinterpret_cast<u32x4*>(&rbl[0]) = Blv[ib + (size_t)g0 * 256];       \
    *reinterpret_cast<u32x4*>(&rbl[4]) = Blv[ib + (size_t)(g0 + 1) * 256]; \
  }

  LOADT(0);

  for (int kt = 0; kt < CH / BK; ++kt) {
    __syncthreads();
    {
      int xa = sn & 7;
      int q0 = ((2 * kq) ^ xa) << 2, q1 = ((2 * kq + 1) ^ xa) << 2;
      int q2 = ((4 + 2 * kq) ^ xa) << 2, q3 = ((5 + 2 * kq) ^ xa) << 2;
      *reinterpret_cast<u32x4*>(&As[sn * 32 + q0]) = *reinterpret_cast<u32x4*>(&rah[0]);
      *reinterpret_cast<u32x4*>(&As[sn * 32 + q1]) = *reinterpret_cast<u32x4*>(&rah[4]);
      *reinterpret_cast<u32x4*>(&As[sn * 32 + q2]) = *reinterpret_cast<u32x4*>(&ral[0]);
      *reinterpret_cast<u32x4*>(&As[sn * 32 + q3]) = *reinterpret_cast<u32x4*>(&ral[4]);
      *reinterpret_cast<u32x4*>(&Bs[sn * 32 + q0]) = *reinterpret_cast<u32x4*>(&rbh[0]);
      *reinterpret_cast<u32x4*>(&Bs[sn * 32 + q1]) = *reinterpret_cast<u32x4*>(&rbh[4]);
      *reinterpret_cast<u32x4*>(&Bs[sn * 32 + q2]) = *reinterpret_cast<u32x4*>(&rbl[0]);
      *reinterpret_cast<u32x4*>(&Bs[sn * 32 + q3]) = *reinterpret_cast<u32x4*>(&rbl[4]);
    }
    __syncthreads();

    if (kt + 1 < CH / BK) LOADT(kt + 1);

    short8 bhf[4], blf[4];
#pragma unroll
    for (int nf = 0; nf < 4; nf++) {
      int nloc = wc * 64 + nf * 16 + fcol;
      bhf[nf] = ldfrag(Bs, nloc, l16);
      blf[nf] = ldfrag(Bs, nloc, 4 + l16);
    }
#pragma unroll
    for (int mf = 0; mf < 4; mf++) {
      int mloc = wr * 64 + mf * 16 + fcol;
      short8 ah = ldfrag(As, mloc, l16);
      short8 al = ldfrag(As, mloc, 4 + l16);
#pragma unroll
      for (int nf = 0; nf < 4; nf++) {
        acc[mf][nf] = __builtin_amdgcn_mfma_f32_16x16x32_bf16(ah, bhf[nf], acc[mf][nf], 0, 0, 0);
        acc[mf][nf] = __builtin_amdgcn_mfma_f32_16x16x32_bf16(ah, blf[nf], acc[mf][nf], 0, 0, 0);
        acc[mf][nf] = __builtin_amdgcn_mfma_f32_16x16x32_bf16(al, bhf[nf], acc[mf][nf], 0, 0, 0);
      }
    }
  }
#undef LOADT

  int rbase = l16 * 4;
#pragma unroll
  for (int mf = 0; mf < 4; mf++) {
    int mbase = cm0 + wr * 64 + mf * 16 + rbase;
#pragma unroll
    for (int r = 0; r < 4; r++) {
#pragma unroll
      for (int nf = 0; nf < 4; nf++) {
        int n = n0 + wc * 64 + nf * 16 + fcol;
        Cout[(size_t)(mbase + r) * HW + n] = acc[mf][nf][r];
      }
    }
  }
}

// ---------------------------------------------------------------------------
// sim GEMM: 256x256 tile, 8 waves, 3-pass, PHASE-SPLIT schedule:
// per K-tile 3 phases (hh / ah*bl / al*bh), slab-granular staging, counted
// vmcnt {10,10,12} (pipeline never drains), setprio MFMA clusters of 32.
// Bit-identical accumulation order to the R9 kernel.
// ---------------------------------------------------------------------------
#define SIMG_NT 32

__global__ __launch_bounds__(512, 2) void simg_k(
    const unsigned* __restrict__ Gh, const unsigned* __restrict__ Gl,
    const float* __restrict__ invc, float* __restrict__ simout,
    unsigned long long* __restrict__ amg) {
  __shared__ __align__(16) unsigned smem[32768];   // 128 KB, 2 x 64 KB bufs

  int orig = (blockIdx.z * 16 + blockIdx.y) * 16 + blockIdx.x;
  int lin = (orig & 7) * 64 + (orig >> 3);         // XCD-contiguous, bijective
  int z = lin >> 8, bx = (lin >> 4) & 15, by = lin & 15;

  const unsigned* srcs[4];
  srcs[0] = Gh + (size_t)z * 2097152 + (size_t)bx * 131072;   // Ah -> slab 0
  srcs[1] = Gl + (size_t)z * 2097152 + (size_t)bx * 131072;   // Al -> slab 1
  srcs[2] = Gh + (size_t)2 * 2097152 + (size_t)by * 131072;   // Bh -> slab 2
  srcs[3] = Gl + (size_t)2 * 2097152 + (size_t)by * 131072;   // Bl -> slab 3

  int tid = threadIdx.x, ln = tid & 63, wv = tid >> 6;
  int wr = wv >> 2, wc = wv & 3;
  int fcol = ln & 15, l16 = ln >> 4;

  f32x4 acc[8][4] = {};

// stage one 16 KB slab OP of tile T into buffer BSEL (2 gloads/thread)
#define STAGE1(BSEL, T, OP)                                                   \
  {                                                                           \
    const unsigned* gs = srcs[OP] + (size_t)(T) * 4096;                       \
    _Pragma("unroll")                                                         \
    for (int rr = 0; rr < 2; rr++) {                                          \
      int off = rr * 2048 + tid * 4;                                          \
      __builtin_amdgcn_global_load_lds(                                       \
          (const __attribute__((address_space(1))) unsigned*)(gs + off),      \
          (__attribute__((address_space(3))) unsigned*)(smem + (BSEL) * 16384 + (OP) * 4096 + off), \
          16, 0, 0);                                                          \
    }                                                                         \
  }

  // prologue (issue order matters for vmcnt accounting):
  STAGE1(0, 0, 0); STAGE1(0, 0, 2);   // AhBh(0)  4
  STAGE1(0, 0, 3);                    // Bl(0)    2
  STAGE1(0, 0, 1);                    // Al(0)    2
  STAGE1(1, 1, 0); STAGE1(1, 1, 2);   // AhBh(1)  4
  STAGE1(1, 1, 3);                    // Bl(1)    2   -> 14 outstanding

  for (int t = 0; t < SIMG_NT; ++t) {
    const unsigned* Sb = smem + (t & 1) * 16384;
    short8 ah[8], bh[4];

    // -------- phase 0: hi(A) x hi(B) --------
    if (t < SIMG_NT - 1) asm volatile("s_waitcnt vmcnt(10)" ::: "memory");
    else                 asm volatile("s_waitcnt vmcnt(4)" ::: "memory");
    __builtin_amdgcn_s_barrier();
    __builtin_amdgcn_sched_barrier(0);
    if (t + 1 < SIMG_NT) STAGE1((t + 1) & 1, t + 1, 1);       // Al(t+1)
#pragma unroll
    for (int nf = 0; nf < 4; nf++)
      bh[nf] = *reinterpret_cast<const short8*>(Sb + 8192 + l16 * 1024 + (wc * 64 + nf * 16 + fcol) * 4);
#pragma unroll
    for (int mf = 0; mf < 8; mf++)
      ah[mf] = *reinterpret_cast<const short8*>(Sb + l16 * 1024 + (wr * 128 + mf * 16 + fcol) * 4);
    __builtin_amdgcn_s_setprio(1);
#pragma unroll
    for (int mf = 0; mf < 8; mf++)
#pragma unroll
      for (int nf = 0; nf < 4; nf++)
        acc[mf][nf] = __builtin_amdgcn_mfma_f32_16x16x32_bf16(ah[mf], bh[nf], acc[mf][nf], 0, 0, 0);
    __builtin_amdgcn_s_setprio(0);

    // -------- phase 1: hi(A) x lo(B) --------
    if (t < SIMG_NT - 1) asm volatile("s_waitcnt vmcnt(10)" ::: "memory");
    else                 asm volatile("s_waitcnt vmcnt(2)" ::: "memory");
    __builtin_amdgcn_s_barrier();
    __builtin_amdgcn_sched_barrier(0);
    if (t + 2 < SIMG_NT) { STAGE1(t & 1, t + 2, 0); STAGE1(t & 1, t + 2, 2); }  // AhBh(t+2)
    {
      short8 bl[4];
#pragma unroll
      for (int nf = 0; nf < 4; nf++)
        bl[nf] = *reinterpret_cast<const short8*>(Sb + 12288 + l16 * 1024 + (wc * 64 + nf * 16 + fcol) * 4);
      __builtin_amdgcn_s_setprio(1);
#pragma unroll
      for (int mf = 0; mf < 8; mf++)
#pragma unroll
        for (int nf = 0; nf < 4; nf++)
          acc[mf][nf] = __builtin_amdgcn_mfma_f32_16x16x32_bf16(ah[mf], bl[nf], acc[mf][nf], 0, 0, 0);
      __builtin_amdgcn_s_setprio(0);
    }

    // -------- phase 2: lo(A) x hi(B) --------
    if (t < SIMG_NT - 2)       asm volatile("s_waitcnt vmcnt(12)" ::: "memory");
    else if (t == SIMG_NT - 2) asm volatile("s_waitcnt vmcnt(8)" ::: "memory");
    else                       asm volatile("s_waitcnt vmcnt(0)" ::: "memory");
    __builtin_amdgcn_s_barrier();
    __builtin_amdgcn_sched_barrier(0);
    if (t + 2 < SIMG_NT) STAGE1(t & 1, t + 2, 3);             // Bl(t+2)
    {
      short8 al[8];
#pragma unroll
      for (int mf = 0; mf < 8; mf++)
        al[mf] = *reinterpret_cast<const short8*>(Sb + 4096 + l16 * 1024 + (wr * 128 + mf * 16 + fcol) * 4);
      __builtin_amdgcn_s_setprio(1);
#pragma unroll
      for (int mf = 0; mf < 8; mf++)
#pragma unroll
        for (int nf = 0; nf < 4; nf++)
          acc[mf][nf] = __builtin_amdgcn_mfma_f32_16x16x32_bf16(al[mf], bh[nf], acc[mf][nf], 0, 0, 0);
      __builtin_amdgcn_s_setprio(0);
    }
  }
#undef STAGE1

  // epilogue: row-scaled C write + fused column-argmax via packed atomicMax
  const float* rs = invc + (size_t)z * HW;
  float* C = simout + (size_t)z * HW * HW;
  unsigned long long* am = amg + (size_t)z * HW;
  int m0 = bx * 256, n0 = by * 256;
  int ncol[4];
#pragma unroll
  for (int nf = 0; nf < 4; nf++) ncol[nf] = n0 + wc * 64 + nf * 16 + fcol;
  float bv[4] = {-FLT_MAX, -FLT_MAX, -FLT_MAX, -FLT_MAX};
  int bi[4] = {0, 0, 0, 0};
#pragma unroll
  for (int mf = 0; mf < 8; mf++) {
    int mg = m0 + wr * 128 + mf * 16 + l16 * 4;
#pragma unroll
    for (int r = 0; r < 4; r++) {
      float sc = rs[mg + r];
#pragma unroll
      for (int nf = 0; nf < 4; nf++) {
        float val = acc[mf][nf][r] * sc;
        C[(size_t)(mg + r) * HW + ncol[nf]] = val;
        if (val > bv[nf]) { bv[nf] = val; bi[nf] = mg + r; }   // ascending m
      }
    }
  }
#pragma unroll
  for (int nf = 0; nf < 4; nf++) {
#pragma unroll
    for (int st = 16; st <= 32; st <<= 1) {
      float ov = __shfl_xor(bv[nf], st, 64);
      int oi = __shfl_xor(bi[nf], st, 64);
      if (ov > bv[nf] || (ov == bv[nf] && oi < bi[nf])) { bv[nf] = ov; bi[nf] = oi; }
    }
  }
  if (ln < 16) {
#pragma unroll
    for (int nf = 0; nf < 4; nf++) {
      unsigned b = __float_as_uint(bv[nf]);
      unsigned key = (b & 0x80000000u) ? ~b : (b | 0x80000000u);
      unsigned long long packed =
          ((unsigned long long)key << 32) | (unsigned)(~bi[nf]);
      atomicMax(am + ncol[nf], packed);
    }
  }
}

__global__ __launch_bounds__(256) void votes_k(const unsigned long long* __restrict__ am,
                                               const int* __restrict__ mask,
                                               float* __restrict__ out) {
  int xy = blockIdx.x * 256 + threadIdx.x;
  int vote = 0;
  for (int s = 0; s < SREF; s++) {
    unsigned long long p = am[(size_t)s * HW + xy];
    int bi = (int)(~(unsigned)p);
    vote += (mask[s * HW + bi] != 0);
  }
  out[xy] = (float)vote;
}

extern "C" void kernel_launch(void* const* d_in, const int* in_sizes, int n_in,
                              void* d_out, int out_size, void* d_ws, size_t ws_size,
                              hipStream_t stream) {
  const float* fmaps = (const float*)d_in[0];
  const int* mask = (const int*)d_in[1];
  const float* basis = (const float*)d_in[2];
  float* out = (float*)d_out;
  float* ws = (float*)d_ws;

  unsigned* fh = (unsigned*)ws;                       // blocked hi plane
  unsigned* fl = (unsigned*)(ws + 6291456);           // blocked lo plane
  float* invn = ws + 12582912;
  float* invc = ws + 12595200;
  float* protos = ws + 12607552;
  float* proto = ws + 12611648;
  unsigned long long* am = (unsigned long long*)(ws + 12612672);   // 2*HW u64
  float* part = ws + 12629056;                        // 8*2048 partials

  float* sim = out;
  float* simfwd = out + 33554432;
  float* votes = out + 33558528;
  unsigned* Ach = (unsigned*)out;                     // blocked Acomb (hi)
  unsigned* Acl = (unsigned*)(out + 786432);          // blocked Acomb (lo)
  float* coef = out + 1572864;
  float* Xd = out + 5767168;

  // 0) zero the packed-argmax array (graph-capture-safe)
  hipMemsetAsync(am, 0, (size_t)SREF * HW * sizeof(unsigned long long), stream);

  // 1) fn = l2norm(fmaps, C) -> blocked split planes (3 frames)
  colnorm_k<<<dim3(TFR * 64), 256, 0, stream>>>(fmaps, invn);
  scale_pack_k<<<dim3(TFR * 2048), 256, 0, stream>>>(fmaps, invn, fh, fl);

  // 2) blocked Acomb: projector + padded basis
  proj_pack_k<<<dim3(16, 16), 256, 0, stream>>>(basis, Ach, Acl);
  pack_basis_k<<<dim3(512), 256, 0, stream>>>(basis, Ach, Acl);

  // 3) batched debias: coef (z<2) + Xd (z=2), full 3-pass
  gemm3d_k<<<dim3(12, 32, 3), 256, 0, stream>>>(Ach, Acl, fh, fl, Xd, coef);
  normref_k<<<dim3(64, 2), 256, 0, stream>>>(coef, invc);

  // 4) tgt renorm + repack into planes frame 2
  colnorm_k<<<dim3(64), 256, 0, stream>>>(Xd, invc + 2 * HW);
  scale_pack_k<<<dim3(2048), 256, 0, stream>>>(Xd, invc + 2 * HW,
                                               fh + (size_t)2 * 2097152,
                                               fl + (size_t)2 * 2097152);

  // 5) prototype (protomv k-split into partials; counts folded into norm)
  proto_k<<<256, 256, 0, stream>>>(fh, fl, mask, invc, protos);
  protomv_k<<<dim3(8, 8), 256, 0, stream>>>(Ach, Acl, protos, part);
  protonorm_k<<<1, 256, 0, stream>>>(part, mask, proto);

  // 6) sim_fwd (widened)
  simfwd_k<<<64, 256, 0, stream>>>(fh, fl, proto, simfwd);

  // 7) sim (256², 3-pass, phase-split pipeline, fused atomic argmax)
  simg_k<<<dim3(16, 16, 2), 512, 0, stream>>>(fh, fl, invc, sim, am);

  // 8) votes
  votes_k<<<16, 256, 0, stream>>>(am, mask, votes);
}